// Round 7
// baseline (202.752 us; speedup 1.0000x reference)
//
#include <hip/hip_runtime.h>
#include <stdint.h>

#define B_  2
#define S_  768
#define D_  768
#define H_  8
#define DH_ 96

typedef unsigned short ushort_t;
typedef __bf16 bf16x8 __attribute__((ext_vector_type(8)));
typedef float  f32x4  __attribute__((ext_vector_type(4)));
typedef _Float16 f16x4 __attribute__((ext_vector_type(4)));

__device__ inline ushort_t f2bf(float f) {
    union { float f; unsigned int u; } v; v.f = f;
    unsigned int u = v.u;
    unsigned int r = u + 0x7fffu + ((u >> 16) & 1u);
    return (ushort_t)(r >> 16);
}
__device__ inline float bf2f(ushort_t u) {
    union { unsigned int i; float f; } c; c.i = ((unsigned int)u) << 16;
    return c.f;
}
__device__ inline ushort_t f2h(float f) {
    union { _Float16 h; ushort_t u; } c; c.h = (_Float16)f; return c.u;
}

// async global->LDS, 16B per lane; LDS dest is wave-uniform base + lane*16.
__device__ inline void glds16(const void* gp, void* lp) {
    auto g = reinterpret_cast<const __attribute__((address_space(1))) uint32_t*>(
        reinterpret_cast<uintptr_t>(gp));
    auto l = reinterpret_cast<__attribute__((address_space(3))) uint32_t*>(
        reinterpret_cast<uintptr_t>(lp));
    __builtin_amdgcn_global_load_lds(g, l, 16, 0, 0);
}

// counted-wait helpers (T4): raw barrier, no vmcnt(0) drain. rule #18 fences.
#define SBAR()  { __builtin_amdgcn_sched_barrier(0); __builtin_amdgcn_s_barrier(); \
                  __builtin_amdgcn_sched_barrier(0); }
#define WAIT_VM(N) { asm volatile("s_waitcnt vmcnt(" #N ")" ::: "memory"); \
                     __builtin_amdgcn_sched_barrier(0); }
#define WAIT_LGKM0() { asm volatile("s_waitcnt lgkmcnt(0)" ::: "memory"); \
                       __builtin_amdgcn_sched_barrier(0); }

// ---------------------------------------------------------------- convert
// X,Wq..Wo -> bf16; dist/ang -> fp16 (into xbuf region, dead until k_out).
__global__ __launch_bounds__(256) void k_convert(
        const float* __restrict__ X, const float* __restrict__ Wq,
        const float* __restrict__ Wk, const float* __restrict__ Wv,
        const float* __restrict__ Wo, const float* __restrict__ distm,
        const float* __restrict__ angm,
        ushort_t* __restrict__ Xb, ushort_t* __restrict__ Wb,
        ushort_t* __restrict__ Dh, ushort_t* __restrict__ Ah) {
    const int NX4 = (B_ * S_ * D_) / 4;   // 294912
    const int NW4 = (D_ * D_) / 4;        // 147456
    const int NWall = 4 * NW4;            // 589824
    const int ND4 = (B_ * S_ * S_) / 4;   // 294912
    int i = blockIdx.x * blockDim.x + threadIdx.x;
    float4 v;
    ushort_t* dst;
    bool h16 = false;
    if (i < NX4) {
        v = ((const float4*)X)[i];
        dst = Xb + i * 4;
    } else if (i < NX4 + NWall) {
        int wi = i - NX4;
        int sel = wi / NW4;
        int off = wi - sel * NW4;
        const float* src = (sel == 0) ? Wq : (sel == 1) ? Wk : (sel == 2) ? Wv : Wo;
        v = ((const float4*)src)[off];
        dst = Wb + wi * 4;
    } else if (i < NX4 + NWall + ND4) {
        int off = i - NX4 - NWall;
        v = ((const float4*)distm)[off];
        dst = Dh + off * 4; h16 = true;
    } else {
        int off = i - NX4 - NWall - ND4;
        v = ((const float4*)angm)[off];
        dst = Ah + off * 4; h16 = true;
    }
    ushort4 o;
    if (h16) { o.x = f2h(v.x); o.y = f2h(v.y); o.z = f2h(v.z); o.w = f2h(v.w); }
    else     { o.x = f2bf(v.x); o.y = f2bf(v.y); o.z = f2bf(v.z); o.w = f2bf(v.w); }
    *(ushort4*)dst = o;
}

// ---------------------------------------------------------------- 64x64 GEMM, dbuf + counted vmcnt
__device__ inline void gemm64_dbuf(
        const ushort_t* __restrict__ A, int lda,
        const ushort_t* __restrict__ Bt, int ldb,
        int K, int m0, int n0,
        ushort_t* As, ushort_t* Bs, f32x4 acc[2][2]) {
    const int tid  = threadIdx.x;
    const int lane = tid & 63, wave = tid >> 6;
    const int wm = (wave >> 1) * 32, wn = (wave & 1) * 32;
    const int fr = lane & 15, fk = (lane >> 4) * 8;
    const ushort_t* Ap = A  + (size_t)(m0 + wave * 16 + (lane >> 2)) * lda + (lane & 3) * 8;
    const ushort_t* Bp = Bt + (size_t)(n0 + wave * 16 + (lane >> 2)) * ldb + (lane & 3) * 8;
    glds16(Ap, As + wave * 512);
    glds16(Bp, Bs + wave * 512);
    for (int kt = 0; kt < K; kt += 32) {
        const int cur = (kt >> 5) & 1;
        if (kt + 32 < K) {
            glds16(Ap + kt + 32, As + (cur ^ 1) * 2048 + wave * 512);
            glds16(Bp + kt + 32, Bs + (cur ^ 1) * 2048 + wave * 512);
            WAIT_VM(2)
        } else {
            WAIT_VM(0)
        }
        SBAR()
        const ushort_t* Ab = As + cur * 2048;
        const ushort_t* Bb = Bs + cur * 2048;
        bf16x8 a0 = *(const bf16x8*)&Ab[(wm      + fr) * 32 + fk];
        bf16x8 a1 = *(const bf16x8*)&Ab[(wm + 16 + fr) * 32 + fk];
        bf16x8 b0 = *(const bf16x8*)&Bb[(wn      + fr) * 32 + fk];
        bf16x8 b1 = *(const bf16x8*)&Bb[(wn + 16 + fr) * 32 + fk];
        acc[0][0] = __builtin_amdgcn_mfma_f32_16x16x32_bf16(a0, b0, acc[0][0], 0, 0, 0);
        acc[0][1] = __builtin_amdgcn_mfma_f32_16x16x32_bf16(a0, b1, acc[0][1], 0, 0, 0);
        acc[1][0] = __builtin_amdgcn_mfma_f32_16x16x32_bf16(a1, b0, acc[1][0], 0, 0, 0);
        acc[1][1] = __builtin_amdgcn_mfma_f32_16x16x32_bf16(a1, b1, acc[1][1], 0, 0, 0);
        WAIT_LGKM0()
        SBAR()
    }
}

// ---------------------------------------------------------------- QKV GEMM (64x64, 864 blocks)
// 864 blocks -> ~8 co-resident blocks/CU: independent barrier-groups hide
// per-phase latency (216-block 128^2 tile had <1 block/CU -> all stalls exposed).
__global__ __launch_bounds__(256) void k_qkv(
        const ushort_t* __restrict__ Xb, const ushort_t* __restrict__ Wb,
        const float* __restrict__ bq, const float* __restrict__ bk,
        const float* __restrict__ bv,
        ushort_t* __restrict__ Qb, ushort_t* __restrict__ Kb,
        ushort_t* __restrict__ Vtb) {
    __shared__ __align__(16) ushort_t As[2 * 64 * 32];
    __shared__ __align__(16) ushort_t Bs[2 * 64 * 32];
    f32x4 acc[2][2];
    #pragma unroll
    for (int i = 0; i < 2; i++)
        #pragma unroll
        for (int j = 0; j < 2; j++) acc[i][j] = (f32x4){0.f, 0.f, 0.f, 0.f};
    const int m0 = blockIdx.y * 64, n0 = blockIdx.x * 64;
    gemm64_dbuf(Xb, D_, Wb, D_, D_, m0, n0, As, Bs, acc);
    const int lane = threadIdx.x & 63, wave = threadIdx.x >> 6;
    const int wm = (wave >> 1) * 32, wn = (wave & 1) * 32;
    #pragma unroll
    for (int ni = 0; ni < 2; ni++) {
        int gcol = n0 + wn + ni * 16 + (lane & 15);
        int gsel = gcol / D_, d768 = gcol - gsel * D_;
        int h = d768 / DH_, d = d768 - h * DH_;
        float bias = (gsel == 0 ? bq : (gsel == 1 ? bk : bv))[d768];
        #pragma unroll
        for (int mi = 0; mi < 2; mi++) {
            int grow0 = m0 + wm + mi * 16 + (lane >> 4) * 4;
            int b = grow0 / S_, s0 = grow0 - b * S_;
            int bh = b * H_ + h;
            if (gsel == 2) {
                ushort4 o4;
                o4.x = f2bf(acc[mi][ni][0] + bias);
                o4.y = f2bf(acc[mi][ni][1] + bias);
                o4.z = f2bf(acc[mi][ni][2] + bias);
                o4.w = f2bf(acc[mi][ni][3] + bias);
                *(ushort4*)&Vtb[((size_t)bh * DH_ + d) * S_ + s0] = o4;
            } else if (gsel == 1) {
                #pragma unroll
                for (int r = 0; r < 4; r++)
                    Kb[(((size_t)bh * 12 + (d >> 3)) * S_ + s0 + r) * 8 + (d & 7)] =
                        f2bf(acc[mi][ni][r] + bias);
            } else {
                #pragma unroll
                for (int r = 0; r < 4; r++)
                    Qb[((size_t)bh * S_ + s0 + r) * DH_ + d] = f2bf(acc[mi][ni][r] + bias);
            }
        }
    }
}

// ---------------------------------------------------------------- fused flash v7
// ALL MFMA operands loaded straight from L2 into registers (no LDS staging, no
// glds, no swizzles): K-frag = 16B contiguous per lane from Kb[grp][s][8];
// dist/ang = 8B fp16 per lane; PV V-frag = 2x8B from Vt[d][s] (the v4 swizzle
// algebra cancels to direct addresses). Only 3 barriers/block (softmax x2,
// ctx-reduce x1); waves otherwise independent -> 12 uncoupled waves/CU hide L2
// latency; compiler software-pipelines the fully-unrolled register loads.
// XCD pin unchanged: idx&15=bh, idx%8=h -> K/V (288KB/bh) L2-resident.
__global__ __launch_bounds__(256, 3) void k_flash(
        const ushort_t* __restrict__ Qb, const ushort_t* __restrict__ Kb,
        const ushort_t* __restrict__ Vtb,
        const float* __restrict__ Wd, const float* __restrict__ bd,
        const float* __restrict__ Wa, const float* __restrict__ ba,
        const ushort_t* __restrict__ Dh, const ushort_t* __restrict__ Ah,
        const float* __restrict__ mask,
        float* __restrict__ probs, ushort_t* __restrict__ Ctxb) {
    __shared__ float mstat[64];
    __shared__ float lstat[64];
    __shared__ float ctxred[1600];          // [16 rows][100]
    const int idx = blockIdx.x;
    const int bh = idx & 15, t = idx >> 4;  // idx%8 == h -> XCD pin
    const int b = bh >> 3, h = bh & 7;
    const int r0 = t * 16;
    const int tid = threadIdx.x, lane = tid & 63, w = tid >> 6;
    const int frn = lane & 15, g = lane >> 4;
    const ushort_t* Qbh = Qb + (size_t)bh * S_ * DH_;
    const ushort_t* Kbh = Kb + (size_t)bh * 12 * S_ * 8;   // [grp][s][8]
    const ushort_t* Vbh = Vtb + (size_t)bh * DH_ * S_;

    // zero ctx tile up front (ordered before atomics by the softmax barriers)
    #pragma unroll
    for (int i = 0; i < 7; ++i) {
        int z = tid + i * 256;
        if (z < 1600) ctxred[z] = 0.f;
    }

    // Q fragments (B operand of swapped QK^T): row = q-row = frn
    bf16x8 aq0, aq1, aq2;
    {
        const ushort_t* qp = Qbh + (size_t)(r0 + frn) * DH_ + g * 8;
        aq0 = *(const bf16x8*)qp;
        aq1 = *(const bf16x8*)(qp + 32);
        aq2 = *(const bf16x8*)(qp + 64);
    }
    // qcoef fused: lane holds q[frn][f*32+8g..+7]; reduce over g (xor 16,32)
    float qc0 = 0.f, qc1 = 0.f, qc2 = 0.f;
    #pragma unroll
    for (int f = 0; f < 3; ++f) {
        bf16x8 aq = (f == 0) ? aq0 : (f == 1) ? aq1 : aq2;
        #pragma unroll
        for (int e = 0; e < 8; ++e) {
            int d = f * 32 + g * 8 + e;
            float qv = (float)aq[e];
            qc0 += qv * Wd[d];
            qc1 += qv * Wa[d];
            qc2 += qv * (bd[d] + ba[d]);
        }
    }
    qc0 += __shfl_xor(qc0, 16); qc0 += __shfl_xor(qc0, 32);
    qc1 += __shfl_xor(qc1, 16); qc1 += __shfl_xor(qc1, 32);
    qc2 += __shfl_xor(qc2, 16); qc2 += __shfl_xor(qc2, 32);

    const float isq = 0.10206207261596577f;   // 1/sqrt(96)

    // ---- loop 1: barrier-free, operands direct from L2
    f32x4 acc[12];
    const ushort_t* kbase = Kbh + ((size_t)g * S_ + 16 * w + frn) * 8;
    const ushort_t* dbase = Dh + (size_t)(b * S_ + r0 + frn) * S_ + w * 16 + g * 4;
    const ushort_t* abase = Ah + (size_t)(b * S_ + r0 + frn) * S_ + w * 16 + g * 4;
    const float*    mbase = mask + b * S_ + w * 16 + g * 4;
    #pragma unroll
    for (int c = 0; c < 12; ++c) {
        const ushort_t* kp = kbase + (size_t)c * 64 * 8;
        bf16x8 k0 = *(const bf16x8*)kp;
        bf16x8 k1 = *(const bf16x8*)(kp + (size_t)4 * S_ * 8);
        bf16x8 k2 = *(const bf16x8*)(kp + (size_t)8 * S_ * 8);
        union { uint2 u; f16x4 hh; } dd, aa;
        dd.u = *(const uint2*)(dbase + c * 64);
        aa.u = *(const uint2*)(abase + c * 64);
        float4 m4 = *(const float4*)(mbase + c * 64);
        f32x4 ca = (f32x4){0.f, 0.f, 0.f, 0.f};
        ca = __builtin_amdgcn_mfma_f32_16x16x32_bf16(k0, aq0, ca, 0, 0, 0);
        ca = __builtin_amdgcn_mfma_f32_16x16x32_bf16(k1, aq1, ca, 0, 0, 0);
        ca = __builtin_amdgcn_mfma_f32_16x16x32_bf16(k2, aq2, ca, 0, 0, 0);
        f32x4 o;
        o[0] = ca[0] * isq + (float)dd.hh[0] * qc0 + (float)aa.hh[0] * qc1 + qc2 + (1.f - m4.x) * -10000.f;
        o[1] = ca[1] * isq + (float)dd.hh[1] * qc0 + (float)aa.hh[1] * qc1 + qc2 + (1.f - m4.y) * -10000.f;
        o[2] = ca[2] * isq + (float)dd.hh[2] * qc0 + (float)aa.hh[2] * qc1 + qc2 + (1.f - m4.z) * -10000.f;
        o[3] = ca[3] * isq + (float)dd.hh[3] * qc0 + (float)aa.hh[3] * qc1 + qc2 + (1.f - m4.w) * -10000.f;
        acc[c] = o;
    }

    // ---- softmax (exact; q-row = frn lane-local; 2 barriers)
    float mx = -1e30f;
    #pragma unroll
    for (int c = 0; c < 12; ++c)
        #pragma unroll
        for (int r = 0; r < 4; ++r) mx = fmaxf(mx, acc[c][r]);
    mx = fmaxf(mx, __shfl_xor(mx, 16));
    mx = fmaxf(mx, __shfl_xor(mx, 32));
    if (g == 0) mstat[w * 16 + frn] = mx;
    __syncthreads();
    float mf = fmaxf(fmaxf(mstat[frn], mstat[16 + frn]),
                     fmaxf(mstat[32 + frn], mstat[48 + frn]));
    float sum = 0.f;
    #pragma unroll
    for (int c = 0; c < 12; ++c)
        #pragma unroll
        for (int r = 0; r < 4; ++r) {
            float e = __expf(acc[c][r] - mf);
            acc[c][r] = e;
            sum += e;
        }
    sum += __shfl_xor(sum, 16);
    sum += __shfl_xor(sum, 32);
    if (g == 0) lstat[w * 16 + frn] = sum;
    __syncthreads();
    float inv = 1.f / (lstat[frn] + lstat[16 + frn] + lstat[32 + frn] + lstat[48 + frn]);

    // ---- loop 2: barrier-free; probs from regs; V direct from L2
    f32x4 accO[6];
    #pragma unroll
    for (int i = 0; i < 6; ++i) accO[i] = (f32x4){0.f, 0.f, 0.f, 0.f};
    float* prow = probs + ((size_t)bh * S_ + r0 + frn) * S_ + w * 16 + g * 4;
    const ushort_t* vbase0 = Vbh + (size_t)frn * S_ + w * 16 + g * 4;
    #pragma unroll
    for (int p = 0; p < 6; ++p) {
        const int c = 2 * p;
        const ushort_t* vb_p = vbase0 + p * 128;
        uint2 v0[6], v1[6];
        #pragma unroll
        for (int nt = 0; nt < 6; ++nt) {
            v0[nt] = *(const uint2*)(vb_p + (size_t)nt * 16 * S_);
            v1[nt] = *(const uint2*)(vb_p + (size_t)nt * 16 * S_ + 64);
        }
        float4 pw;
        pw.x = acc[c][0] * inv; pw.y = acc[c][1] * inv;
        pw.z = acc[c][2] * inv; pw.w = acc[c][3] * inv;
        *(float4*)(prow + c * 64) = pw;
        pw.x = acc[c + 1][0] * inv; pw.y = acc[c + 1][1] * inv;
        pw.z = acc[c + 1][2] * inv; pw.w = acc[c + 1][3] * inv;
        *(float4*)(prow + (c + 1) * 64) = pw;
        // A operand: P[q-row frn][kappa 8g+e]; e<4 -> chunk c, e>=4 -> chunk c+1
        union { bf16x8 v; ushort_t u[8]; } pa;
        #pragma unroll
        for (int r = 0; r < 4; ++r) {
            pa.u[r]     = f2bf(acc[c][r]);
            pa.u[r + 4] = f2bf(acc[c + 1][r]);
        }
        #pragma unroll
        for (int nt = 0; nt < 6; ++nt) {
            union { bf16x8 v; uint2 q2[2]; } vb;
            vb.q2[0] = v0[nt];
            vb.q2[1] = v1[nt];
            accO[nt] = __builtin_amdgcn_mfma_f32_16x16x32_bf16(pa.v, vb.v, accO[nt], 0, 0, 0);
        }
    }

    // ---- cross-wave reduce (kappa-slice partials) + ctx write (1 barrier)
    #pragma unroll
    for (int nt = 0; nt < 6; ++nt)
        #pragma unroll
        for (int r = 0; r < 4; ++r)
            atomicAdd(&ctxred[(4 * g + r) * 100 + nt * 16 + frn], accO[nt][r]);
    __syncthreads();
    {
        int zr = tid >> 4, zc = tid & 15;
        float ivr = 1.f / (lstat[zr] + lstat[16 + zr] + lstat[32 + zr] + lstat[48 + zr]);
        ushort_t* crow = Ctxb + ((size_t)b * S_ + r0 + zr) * D_ + h * DH_;
        #pragma unroll
        for (int i = 0; i < 6; ++i)
            crow[i * 16 + zc] = f2bf(ctxred[zr * 100 + i * 16 + zc] * ivr);
    }
}

// ---------------------------------------------------------------- out GEMM + bias + residual
__global__ __launch_bounds__(256) void k_out(
        const ushort_t* __restrict__ Ctxb, const ushort_t* __restrict__ Wob,
        const float* __restrict__ bo, const float* __restrict__ hidden,
        float* __restrict__ xbuf) {
    __shared__ __align__(16) ushort_t As[2 * 64 * 32];
    __shared__ __align__(16) ushort_t Bs[2 * 64 * 32];
    f32x4 acc[2][2];
    #pragma unroll
    for (int i = 0; i < 2; i++)
        #pragma unroll
        for (int j = 0; j < 2; j++) acc[i][j] = (f32x4){0.f, 0.f, 0.f, 0.f};
    const int m0 = blockIdx.y * 64, n0 = blockIdx.x * 64;
    gemm64_dbuf(Ctxb, D_, Wob, D_, D_, m0, n0, As, Bs, acc);
    const int lane = threadIdx.x & 63, wave = threadIdx.x >> 6;
    const int wm = (wave >> 1) * 32, wn = (wave & 1) * 32;
    #pragma unroll
    for (int ni = 0; ni < 2; ni++) {
        int gcol = n0 + wn + ni * 16 + (lane & 15);
        float bias = bo[gcol];
        #pragma unroll
        for (int mi = 0; mi < 2; mi++) {
            #pragma unroll
            for (int r = 0; r < 4; r++) {
                int grow = m0 + wm + mi * 16 + (lane >> 4) * 4 + r;
                xbuf[(size_t)grow * D_ + gcol] =
                    acc[mi][ni][r] + bias + hidden[(size_t)grow * D_ + gcol];
            }
        }
    }
}

// ---------------------------------------------------------------- LayerNorm
__global__ __launch_bounds__(256) void k_ln(
        const float* __restrict__ xbuf, const float* __restrict__ g,
        const float* __restrict__ bb, float* __restrict__ out) {
    const float* x = xbuf + (size_t)blockIdx.x * D_;
    const int t = threadIdx.x;
    float a0 = x[t], a1 = x[t + 256], a2 = x[t + 512];
    float s = a0 + a1 + a2;
    float ss = a0 * a0 + a1 * a1 + a2 * a2;
    __shared__ float r1[4], r2[4];
    #pragma unroll
    for (int o = 32; o > 0; o >>= 1) { s += __shfl_down(s, o); ss += __shfl_down(ss, o); }
    if ((t & 63) == 0) { r1[t >> 6] = s; r2[t >> 6] = ss; }
    __syncthreads();
    float ts = r1[0] + r1[1] + r1[2] + r1[3];
    float tss = r2[0] + r2[1] + r2[2] + r2[3];
    float mu = ts * (1.0f / D_);
    float var = tss * (1.0f / D_) - mu * mu;
    float rstd = rsqrtf(var + 1e-5f);
    float* o = out + (size_t)blockIdx.x * D_;
    o[t]       = (a0 - mu) * rstd * g[t]       + bb[t];
    o[t + 256] = (a1 - mu) * rstd * g[t + 256] + bb[t + 256];
    o[t + 512] = (a2 - mu) * rstd * g[t + 512] + bb[t + 512];
}

// ---------------------------------------------------------------- launch
extern "C" void kernel_launch(void* const* d_in, const int* in_sizes, int n_in,
                              void* d_out, int out_size, void* d_ws, size_t ws_size,
                              hipStream_t stream) {
    const float* X     = (const float*)d_in[0];
    const float* distm = (const float*)d_in[1];
    const float* angm  = (const float*)d_in[2];
    const float* mask  = (const float*)d_in[3];
    const float* Wq    = (const float*)d_in[4];
    const float* bq    = (const float*)d_in[5];
    const float* Wk    = (const float*)d_in[6];
    const float* bk    = (const float*)d_in[7];
    const float* Wv    = (const float*)d_in[8];
    const float* bv    = (const float*)d_in[9];
    const float* Wd    = (const float*)d_in[10];
    const float* bd    = (const float*)d_in[11];
    const float* Wa    = (const float*)d_in[12];
    const float* ba    = (const float*)d_in[13];
    const float* Wo    = (const float*)d_in[14];
    const float* bo    = (const float*)d_in[15];
    const float* ln_g  = (const float*)d_in[16];
    const float* ln_b  = (const float*)d_in[17];

    float* outp  = (float*)d_out;                        // [B,S,D]
    float* probs = (float*)d_out + (size_t)B_ * S_ * D_; // [B,H,S,S]

    char* ws = (char*)d_ws;
    ushort_t* Xb    = (ushort_t*)(ws + 0);          // 2,359,296 B
    ushort_t* Wb    = (ushort_t*)(ws + 2359296);    // 4,718,592 B
    ushort_t* Qb    = (ushort_t*)(ws + 7077888);    // 2,359,296 B
    ushort_t* Kb    = (ushort_t*)(ws + 9437184);    // 2,359,296 B  [bh][grp][s][8]
    ushort_t* Vtb   = (ushort_t*)(ws + 11796480);   // 2,359,296 B
    ushort_t* Ctxb  = (ushort_t*)(ws + 14155776);   // 2,359,296 B
    float*    xbuf  = (float*)   (ws + 16662528);   // 4,718,592 B (end ~21.4 MB)
    // Dh/Ah (fp16 dist/ang) alias xbuf: written by k_convert, read by k_flash,
    // dead once k_out overwrites xbuf (stream-ordered).
    ushort_t* Dh    = (ushort_t*)(ws + 16662528);   // 2,359,296 B
    ushort_t* Ah    = (ushort_t*)(ws + 16662528 + 2359296);

    k_convert<<<5760, 256, 0, stream>>>(X, Wq, Wk, Wv, Wo, distm, angm, Xb, Wb, Dh, Ah);
    k_qkv<<<dim3(36, 24), 256, 0, stream>>>(Xb, Wb, bq, bk, bv, Qb, Kb, Vtb);
    k_flash<<<768, 256, 0, stream>>>(Qb, Kb, Vtb, Wd, bd, Wa, ba, Dh, Ah, mask, probs, Ctxb);
    k_out<<<dim3(12, 24), 256, 0, stream>>>(Ctxb, Wb + (size_t)2304 * 768, bo, X, xbuf);
    k_ln<<<1536, 256, 0, stream>>>(xbuf, ln_g, ln_b, outp);
}

// Round 8
// 182.489 us; speedup vs baseline: 1.1110x; 1.1110x over previous
//
#include <hip/hip_runtime.h>
#include <stdint.h>

#define B_  2
#define S_  768
#define D_  768
#define H_  8
#define DH_ 96

typedef unsigned short ushort_t;
typedef __bf16 bf16x8 __attribute__((ext_vector_type(8)));
typedef float  f32x4  __attribute__((ext_vector_type(4)));
typedef _Float16 f16x4 __attribute__((ext_vector_type(4)));

__device__ inline ushort_t f2bf(float f) {
    union { float f; unsigned int u; } v; v.f = f;
    unsigned int u = v.u;
    unsigned int r = u + 0x7fffu + ((u >> 16) & 1u);
    return (ushort_t)(r >> 16);
}
__device__ inline float bf2f(ushort_t u) {
    union { unsigned int i; float f; } c; c.i = ((unsigned int)u) << 16;
    return c.f;
}
__device__ inline ushort_t f2h(float f) {
    union { _Float16 h; ushort_t u; } c; c.h = (_Float16)f; return c.u;
}

// async global->LDS, 16B per lane; LDS dest is wave-uniform base + lane*16.
__device__ inline void glds16(const void* gp, void* lp) {
    auto g = reinterpret_cast<const __attribute__((address_space(1))) uint32_t*>(
        reinterpret_cast<uintptr_t>(gp));
    auto l = reinterpret_cast<__attribute__((address_space(3))) uint32_t*>(
        reinterpret_cast<uintptr_t>(lp));
    __builtin_amdgcn_global_load_lds(g, l, 16, 0, 0);
}

// counted-wait helpers (T4): raw barrier, no vmcnt(0) drain. rule #18 fences.
#define SBAR()  { __builtin_amdgcn_sched_barrier(0); __builtin_amdgcn_s_barrier(); \
                  __builtin_amdgcn_sched_barrier(0); }
#define WAIT_VM(N) { asm volatile("s_waitcnt vmcnt(" #N ")" ::: "memory"); \
                     __builtin_amdgcn_sched_barrier(0); }
#define WAIT_LGKM0() { asm volatile("s_waitcnt lgkmcnt(0)" ::: "memory"); \
                       __builtin_amdgcn_sched_barrier(0); }

// ---------------------------------------------------------------- convert
// blocks < 3456: X,Wq..Wo -> bf16 linear.
// blocks >= 3456: dist/ang -> fp16 TRANSPOSED-PACKED Dt[b][s/4][row][4] via
// LDS 64x65 tile (2-way-free banks), so k_flash's per-lane 8B reads coalesce.
__global__ __launch_bounds__(256) void k_convert(
        const float* __restrict__ X, const float* __restrict__ Wq,
        const float* __restrict__ Wk, const float* __restrict__ Wv,
        const float* __restrict__ Wo, const float* __restrict__ distm,
        const float* __restrict__ angm,
        ushort_t* __restrict__ Xb, ushort_t* __restrict__ Wb,
        ushort_t* __restrict__ Dh, ushort_t* __restrict__ Ah) {
    __shared__ float tlds[64][65];
    const int NX4 = (B_ * S_ * D_) / 4;   // 294912
    const int NW4 = (D_ * D_) / 4;        // 147456
    const int bid = blockIdx.x, tid = threadIdx.x;
    if (bid < 3456) {
        int i = bid * 256 + tid;
        float4 v;
        ushort_t* dst;
        if (i < NX4) {
            v = ((const float4*)X)[i];
            dst = Xb + i * 4;
        } else {
            int wi = i - NX4;
            int sel = wi / NW4;
            int off = wi - sel * NW4;
            const float* src = (sel == 0) ? Wq : (sel == 1) ? Wk : (sel == 2) ? Wv : Wo;
            v = ((const float4*)src)[off];
            dst = Wb + wi * 4;
        }
        ushort4 o;
        o.x = f2bf(v.x); o.y = f2bf(v.y); o.z = f2bf(v.z); o.w = f2bf(v.w);
        *(ushort4*)dst = o;
        return;
    }
    // transpose tiles: 576 blocks = 2 mats x 2 b x 12 rt x 12 ct
    int tidx = bid - 3456;
    int mat = tidx / 288, t2 = tidx - mat * 288;
    int b = t2 / 144, t3 = t2 - b * 144;
    int rt = t3 / 12, ct = t3 - rt * 12;
    const float* src = (mat ? angm : distm) + ((size_t)(b * S_ + rt * 64)) * S_ + ct * 64;
    ushort_t* dstm = mat ? Ah : Dh;
    {
        int tr = tid >> 4, tc4 = tid & 15;
        #pragma unroll
        for (int k = 0; k < 4; ++k) {
            int row = tr + k * 16;
            float4 v4 = *(const float4*)(src + (size_t)row * S_ + tc4 * 4);
            tlds[row][tc4 * 4 + 0] = v4.x;
            tlds[row][tc4 * 4 + 1] = v4.y;
            tlds[row][tc4 * 4 + 2] = v4.z;
            tlds[row][tc4 * 4 + 3] = v4.w;
        }
    }
    __syncthreads();
    {
        int row = tid & 63, s4b = tid >> 6;
        #pragma unroll
        for (int k = 0; k < 4; ++k) {
            int s4l = s4b * 4 + k;
            ushort4 o4;
            o4.x = f2h(tlds[row][s4l * 4 + 0]);
            o4.y = f2h(tlds[row][s4l * 4 + 1]);
            o4.z = f2h(tlds[row][s4l * 4 + 2]);
            o4.w = f2h(tlds[row][s4l * 4 + 3]);
            *(ushort4*)&dstm[(((size_t)b * 192 + ct * 16 + s4l) * 768 + rt * 64 + row) * 4] = o4;
        }
    }
}

// ---------------------------------------------------------------- 64x64 GEMM, dbuf + counted vmcnt
__device__ inline void gemm64_dbuf(
        const ushort_t* __restrict__ A, int lda,
        const ushort_t* __restrict__ Bt, int ldb,
        int K, int m0, int n0,
        ushort_t* As, ushort_t* Bs, f32x4 acc[2][2]) {
    const int tid  = threadIdx.x;
    const int lane = tid & 63, wave = tid >> 6;
    const int wm = (wave >> 1) * 32, wn = (wave & 1) * 32;
    const int fr = lane & 15, fk = (lane >> 4) * 8;
    const ushort_t* Ap = A  + (size_t)(m0 + wave * 16 + (lane >> 2)) * lda + (lane & 3) * 8;
    const ushort_t* Bp = Bt + (size_t)(n0 + wave * 16 + (lane >> 2)) * ldb + (lane & 3) * 8;
    glds16(Ap, As + wave * 512);
    glds16(Bp, Bs + wave * 512);
    for (int kt = 0; kt < K; kt += 32) {
        const int cur = (kt >> 5) & 1;
        if (kt + 32 < K) {
            glds16(Ap + kt + 32, As + (cur ^ 1) * 2048 + wave * 512);
            glds16(Bp + kt + 32, Bs + (cur ^ 1) * 2048 + wave * 512);
            WAIT_VM(2)
        } else {
            WAIT_VM(0)
        }
        SBAR()
        const ushort_t* Ab = As + cur * 2048;
        const ushort_t* Bb = Bs + cur * 2048;
        bf16x8 a0 = *(const bf16x8*)&Ab[(wm      + fr) * 32 + fk];
        bf16x8 a1 = *(const bf16x8*)&Ab[(wm + 16 + fr) * 32 + fk];
        bf16x8 b0 = *(const bf16x8*)&Bb[(wn      + fr) * 32 + fk];
        bf16x8 b1 = *(const bf16x8*)&Bb[(wn + 16 + fr) * 32 + fk];
        acc[0][0] = __builtin_amdgcn_mfma_f32_16x16x32_bf16(a0, b0, acc[0][0], 0, 0, 0);
        acc[0][1] = __builtin_amdgcn_mfma_f32_16x16x32_bf16(a0, b1, acc[0][1], 0, 0, 0);
        acc[1][0] = __builtin_amdgcn_mfma_f32_16x16x32_bf16(a1, b0, acc[1][0], 0, 0, 0);
        acc[1][1] = __builtin_amdgcn_mfma_f32_16x16x32_bf16(a1, b1, acc[1][1], 0, 0, 0);
        WAIT_LGKM0()
        SBAR()
    }
}

// ---------------------------------------------------------------- QKV GEMM (64x64, 864 blocks)
// V written in flash fragment order Vf[bh][p][w][nt][lane][8] (bijective remap,
// same ushort4 granularity) so flash's PV loads are 1KB-dense per instruction.
__global__ __launch_bounds__(256) void k_qkv(
        const ushort_t* __restrict__ Xb, const ushort_t* __restrict__ Wb,
        const float* __restrict__ bq, const float* __restrict__ bk,
        const float* __restrict__ bv,
        ushort_t* __restrict__ Qb, ushort_t* __restrict__ Kb,
        ushort_t* __restrict__ Vtb) {
    __shared__ __align__(16) ushort_t As[2 * 64 * 32];
    __shared__ __align__(16) ushort_t Bs[2 * 64 * 32];
    f32x4 acc[2][2];
    #pragma unroll
    for (int i = 0; i < 2; i++)
        #pragma unroll
        for (int j = 0; j < 2; j++) acc[i][j] = (f32x4){0.f, 0.f, 0.f, 0.f};
    const int m0 = blockIdx.y * 64, n0 = blockIdx.x * 64;
    gemm64_dbuf(Xb, D_, Wb, D_, D_, m0, n0, As, Bs, acc);
    const int lane = threadIdx.x & 63, wave = threadIdx.x >> 6;
    const int wm = (wave >> 1) * 32, wn = (wave & 1) * 32;
    #pragma unroll
    for (int ni = 0; ni < 2; ni++) {
        int gcol = n0 + wn + ni * 16 + (lane & 15);
        int gsel = gcol / D_, d768 = gcol - gsel * D_;
        int h = d768 / DH_, d = d768 - h * DH_;
        float bias = (gsel == 0 ? bq : (gsel == 1 ? bk : bv))[d768];
        #pragma unroll
        for (int mi = 0; mi < 2; mi++) {
            int grow0 = m0 + wm + mi * 16 + (lane >> 4) * 4;
            int b = grow0 / S_, s0 = grow0 - b * S_;
            int bh = b * H_ + h;
            if (gsel == 2) {
                ushort4 o4;
                o4.x = f2bf(acc[mi][ni][0] + bias);
                o4.y = f2bf(acc[mi][ni][1] + bias);
                o4.z = f2bf(acc[mi][ni][2] + bias);
                o4.w = f2bf(acc[mi][ni][3] + bias);
                int p = s0 >> 7, wv = (s0 >> 4) & 3, gq = (s0 >> 2) & 3;
                int e0 = (s0 >> 6) & 1;
                size_t off = ((size_t)bh * 73728) + p * 12288 + wv * 3072
                           + (d >> 4) * 512 + (gq * 16 + (d & 15)) * 8 + e0 * 4;
                *(ushort4*)&Vtb[off] = o4;
            } else if (gsel == 1) {
                #pragma unroll
                for (int r = 0; r < 4; r++)
                    Kb[(((size_t)bh * 12 + (d >> 3)) * S_ + s0 + r) * 8 + (d & 7)] =
                        f2bf(acc[mi][ni][r] + bias);
            } else {
                #pragma unroll
                for (int r = 0; r < 4; r++)
                    Qb[((size_t)bh * S_ + s0 + r) * DH_ + d] = f2bf(acc[mi][ni][r] + bias);
            }
        }
    }
}

// ---------------------------------------------------------------- fused flash v8
// v7 structure (register-direct, 3 barriers, XCD pin) but ALL load instructions
// dense: K 4x256B segments; dist/ang from transposed-packed Dt (4x128B); V from
// fragment-ordered Vf (1KB per instruction). No LDS except stats/ctxred.
__global__ __launch_bounds__(256, 3) void k_flash(
        const ushort_t* __restrict__ Qb, const ushort_t* __restrict__ Kb,
        const ushort_t* __restrict__ Vtb,
        const float* __restrict__ Wd, const float* __restrict__ bd,
        const float* __restrict__ Wa, const float* __restrict__ ba,
        const ushort_t* __restrict__ Dh, const ushort_t* __restrict__ Ah,
        const float* __restrict__ mask,
        float* __restrict__ probs, ushort_t* __restrict__ Ctxb) {
    __shared__ float mstat[64];
    __shared__ float lstat[64];
    __shared__ float ctxred[1600];          // [16 rows][100]
    const int idx = blockIdx.x;
    const int bh = idx & 15, t = idx >> 4;  // idx%8 == h -> XCD pin
    const int b = bh >> 3, h = bh & 7;
    const int r0 = t * 16;
    const int tid = threadIdx.x, lane = tid & 63, w = tid >> 6;
    const int frn = lane & 15, g = lane >> 4;
    const ushort_t* Qbh = Qb + (size_t)bh * S_ * DH_;
    const ushort_t* Kbh = Kb + (size_t)bh * 12 * S_ * 8;   // [grp][s][8]

    // zero ctx tile up front (ordered before atomics by the softmax barriers)
    #pragma unroll
    for (int i = 0; i < 7; ++i) {
        int z = tid + i * 256;
        if (z < 1600) ctxred[z] = 0.f;
    }

    // Q fragments (B operand of swapped QK^T): row = q-row = frn
    bf16x8 aq0, aq1, aq2;
    {
        const ushort_t* qp = Qbh + (size_t)(r0 + frn) * DH_ + g * 8;
        aq0 = *(const bf16x8*)qp;
        aq1 = *(const bf16x8*)(qp + 32);
        aq2 = *(const bf16x8*)(qp + 64);
    }
    // qcoef fused: lane holds q[frn][f*32+8g..+7]; reduce over g (xor 16,32)
    float qc0 = 0.f, qc1 = 0.f, qc2 = 0.f;
    #pragma unroll
    for (int f = 0; f < 3; ++f) {
        bf16x8 aq = (f == 0) ? aq0 : (f == 1) ? aq1 : aq2;
        #pragma unroll
        for (int e = 0; e < 8; ++e) {
            int d = f * 32 + g * 8 + e;
            float qv = (float)aq[e];
            qc0 += qv * Wd[d];
            qc1 += qv * Wa[d];
            qc2 += qv * (bd[d] + ba[d]);
        }
    }
    qc0 += __shfl_xor(qc0, 16); qc0 += __shfl_xor(qc0, 32);
    qc1 += __shfl_xor(qc1, 16); qc1 += __shfl_xor(qc1, 32);
    qc2 += __shfl_xor(qc2, 16); qc2 += __shfl_xor(qc2, 32);

    const float isq = 0.10206207261596577f;   // 1/sqrt(96)

    // ---- loop 1: barrier-free, dense operands direct from L2
    f32x4 acc[12];
    const ushort_t* kbase = Kbh + ((size_t)g * S_ + 16 * w + frn) * 8;
    // Dt[b][s4][row][4] fp16, s4 = c*16 + w*4 + g
    const ushort_t* dbase = Dh + ((size_t)(b * 192 + w * 4 + g) * 768 + r0 + frn) * 4;
    const ushort_t* abase = Ah + ((size_t)(b * 192 + w * 4 + g) * 768 + r0 + frn) * 4;
    const float*    mbase = mask + b * S_ + w * 16 + g * 4;
    #pragma unroll
    for (int c = 0; c < 12; ++c) {
        const ushort_t* kp = kbase + (size_t)c * 64 * 8;
        bf16x8 k0 = *(const bf16x8*)kp;
        bf16x8 k1 = *(const bf16x8*)(kp + (size_t)4 * S_ * 8);
        bf16x8 k2 = *(const bf16x8*)(kp + (size_t)8 * S_ * 8);
        union { uint2 u; f16x4 hh; } dd, aa;
        dd.u = *(const uint2*)(dbase + (size_t)c * 16 * 768 * 4);
        aa.u = *(const uint2*)(abase + (size_t)c * 16 * 768 * 4);
        float4 m4 = *(const float4*)(mbase + c * 64);
        f32x4 ca = (f32x4){0.f, 0.f, 0.f, 0.f};
        ca = __builtin_amdgcn_mfma_f32_16x16x32_bf16(k0, aq0, ca, 0, 0, 0);
        ca = __builtin_amdgcn_mfma_f32_16x16x32_bf16(k1, aq1, ca, 0, 0, 0);
        ca = __builtin_amdgcn_mfma_f32_16x16x32_bf16(k2, aq2, ca, 0, 0, 0);
        f32x4 o;
        o[0] = ca[0] * isq + (float)dd.hh[0] * qc0 + (float)aa.hh[0] * qc1 + qc2 + (1.f - m4.x) * -10000.f;
        o[1] = ca[1] * isq + (float)dd.hh[1] * qc0 + (float)aa.hh[1] * qc1 + qc2 + (1.f - m4.y) * -10000.f;
        o[2] = ca[2] * isq + (float)dd.hh[2] * qc0 + (float)aa.hh[2] * qc1 + qc2 + (1.f - m4.z) * -10000.f;
        o[3] = ca[3] * isq + (float)dd.hh[3] * qc0 + (float)aa.hh[3] * qc1 + qc2 + (1.f - m4.w) * -10000.f;
        acc[c] = o;
    }

    // ---- softmax (exact; q-row = frn lane-local; 2 barriers)
    float mx = -1e30f;
    #pragma unroll
    for (int c = 0; c < 12; ++c)
        #pragma unroll
        for (int r = 0; r < 4; ++r) mx = fmaxf(mx, acc[c][r]);
    mx = fmaxf(mx, __shfl_xor(mx, 16));
    mx = fmaxf(mx, __shfl_xor(mx, 32));
    if (g == 0) mstat[w * 16 + frn] = mx;
    __syncthreads();
    float mf = fmaxf(fmaxf(mstat[frn], mstat[16 + frn]),
                     fmaxf(mstat[32 + frn], mstat[48 + frn]));
    float sum = 0.f;
    #pragma unroll
    for (int c = 0; c < 12; ++c)
        #pragma unroll
        for (int r = 0; r < 4; ++r) {
            float e = __expf(acc[c][r] - mf);
            acc[c][r] = e;
            sum += e;
        }
    sum += __shfl_xor(sum, 16);
    sum += __shfl_xor(sum, 32);
    if (g == 0) lstat[w * 16 + frn] = sum;
    __syncthreads();
    float inv = 1.f / (lstat[frn] + lstat[16 + frn] + lstat[32 + frn] + lstat[48 + frn]);

    // ---- loop 2: barrier-free; probs from regs; V fragment-dense from L2
    f32x4 accO[6];
    #pragma unroll
    for (int i = 0; i < 6; ++i) accO[i] = (f32x4){0.f, 0.f, 0.f, 0.f};
    float* prow = probs + ((size_t)bh * S_ + r0 + frn) * S_ + w * 16 + g * 4;
    const ushort_t* vfb = Vtb + (size_t)bh * 73728 + w * 3072 + lane * 8;
    #pragma unroll
    for (int p = 0; p < 6; ++p) {
        const int c = 2 * p;
        bf16x8 vfrag[6];
        #pragma unroll
        for (int nt = 0; nt < 6; ++nt)
            vfrag[nt] = *(const bf16x8*)(vfb + p * 12288 + nt * 512);
        float4 pw;
        pw.x = acc[c][0] * inv; pw.y = acc[c][1] * inv;
        pw.z = acc[c][2] * inv; pw.w = acc[c][3] * inv;
        *(float4*)(prow + c * 64) = pw;
        pw.x = acc[c + 1][0] * inv; pw.y = acc[c + 1][1] * inv;
        pw.z = acc[c + 1][2] * inv; pw.w = acc[c + 1][3] * inv;
        *(float4*)(prow + (c + 1) * 64) = pw;
        // A operand: P[q-row frn][kappa 8g+e]; e<4 -> chunk c, e>=4 -> chunk c+1
        union { bf16x8 v; ushort_t u[8]; } pa;
        #pragma unroll
        for (int r = 0; r < 4; ++r) {
            pa.u[r]     = f2bf(acc[c][r]);
            pa.u[r + 4] = f2bf(acc[c + 1][r]);
        }
        #pragma unroll
        for (int nt = 0; nt < 6; ++nt)
            accO[nt] = __builtin_amdgcn_mfma_f32_16x16x32_bf16(pa.v, vfrag[nt], accO[nt], 0, 0, 0);
    }

    // ---- cross-wave reduce (kappa-slice partials) + ctx write (1 barrier)
    #pragma unroll
    for (int nt = 0; nt < 6; ++nt)
        #pragma unroll
        for (int r = 0; r < 4; ++r)
            atomicAdd(&ctxred[(4 * g + r) * 100 + nt * 16 + frn], accO[nt][r]);
    __syncthreads();
    {
        int zr = tid >> 4, zc = tid & 15;
        float ivr = 1.f / (lstat[zr] + lstat[16 + zr] + lstat[32 + zr] + lstat[48 + zr]);
        ushort_t* crow = Ctxb + ((size_t)b * S_ + r0 + zr) * D_ + h * DH_;
        #pragma unroll
        for (int i = 0; i < 6; ++i)
            crow[i * 16 + zc] = f2bf(ctxred[zr * 100 + i * 16 + zc] * ivr);
    }
}

// ---------------------------------------------------------------- out GEMM + bias + residual
__global__ __launch_bounds__(256) void k_out(
        const ushort_t* __restrict__ Ctxb, const ushort_t* __restrict__ Wob,
        const float* __restrict__ bo, const float* __restrict__ hidden,
        float* __restrict__ xbuf) {
    __shared__ __align__(16) ushort_t As[2 * 64 * 32];
    __shared__ __align__(16) ushort_t Bs[2 * 64 * 32];
    f32x4 acc[2][2];
    #pragma unroll
    for (int i = 0; i < 2; i++)
        #pragma unroll
        for (int j = 0; j < 2; j++) acc[i][j] = (f32x4){0.f, 0.f, 0.f, 0.f};
    const int m0 = blockIdx.y * 64, n0 = blockIdx.x * 64;
    gemm64_dbuf(Ctxb, D_, Wob, D_, D_, m0, n0, As, Bs, acc);
    const int lane = threadIdx.x & 63, wave = threadIdx.x >> 6;
    const int wm = (wave >> 1) * 32, wn = (wave & 1) * 32;
    #pragma unroll
    for (int ni = 0; ni < 2; ni++) {
        int gcol = n0 + wn + ni * 16 + (lane & 15);
        float bias = bo[gcol];
        #pragma unroll
        for (int mi = 0; mi < 2; mi++) {
            #pragma unroll
            for (int r = 0; r < 4; r++) {
                int grow = m0 + wm + mi * 16 + (lane >> 4) * 4 + r;
                xbuf[(size_t)grow * D_ + gcol] =
                    acc[mi][ni][r] + bias + hidden[(size_t)grow * D_ + gcol];
            }
        }
    }
}

// ---------------------------------------------------------------- LayerNorm
__global__ __launch_bounds__(256) void k_ln(
        const float* __restrict__ xbuf, const float* __restrict__ g,
        const float* __restrict__ bb, float* __restrict__ out) {
    const float* x = xbuf + (size_t)blockIdx.x * D_;
    const int t = threadIdx.x;
    float a0 = x[t], a1 = x[t + 256], a2 = x[t + 512];
    float s = a0 + a1 + a2;
    float ss = a0 * a0 + a1 * a1 + a2 * a2;
    __shared__ float r1[4], r2[4];
    #pragma unroll
    for (int o = 32; o > 0; o >>= 1) { s += __shfl_down(s, o); ss += __shfl_down(ss, o); }
    if ((t & 63) == 0) { r1[t >> 6] = s; r2[t >> 6] = ss; }
    __syncthreads();
    float ts = r1[0] + r1[1] + r1[2] + r1[3];
    float tss = r2[0] + r2[1] + r2[2] + r2[3];
    float mu = ts * (1.0f / D_);
    float var = tss * (1.0f / D_) - mu * mu;
    float rstd = rsqrtf(var + 1e-5f);
    float* o = out + (size_t)blockIdx.x * D_;
    o[t]       = (a0 - mu) * rstd * g[t]       + bb[t];
    o[t + 256] = (a1 - mu) * rstd * g[t + 256] + bb[t + 256];
    o[t + 512] = (a2 - mu) * rstd * g[t + 512] + bb[t + 512];
}

// ---------------------------------------------------------------- launch
extern "C" void kernel_launch(void* const* d_in, const int* in_sizes, int n_in,
                              void* d_out, int out_size, void* d_ws, size_t ws_size,
                              hipStream_t stream) {
    const float* X     = (const float*)d_in[0];
    const float* distm = (const float*)d_in[1];
    const float* angm  = (const float*)d_in[2];
    const float* mask  = (const float*)d_in[3];
    const float* Wq    = (const float*)d_in[4];
    const float* bq    = (const float*)d_in[5];
    const float* Wk    = (const float*)d_in[6];
    const float* bk    = (const float*)d_in[7];
    const float* Wv    = (const float*)d_in[8];
    const float* bv    = (const float*)d_in[9];
    const float* Wd    = (const float*)d_in[10];
    const float* bd    = (const float*)d_in[11];
    const float* Wa    = (const float*)d_in[12];
    const float* ba    = (const float*)d_in[13];
    const float* Wo    = (const float*)d_in[14];
    const float* bo    = (const float*)d_in[15];
    const float* ln_g  = (const float*)d_in[16];
    const float* ln_b  = (const float*)d_in[17];

    float* outp  = (float*)d_out;                        // [B,S,D]
    float* probs = (float*)d_out + (size_t)B_ * S_ * D_; // [B,H,S,S]

    char* ws = (char*)d_ws;
    ushort_t* Xb    = (ushort_t*)(ws + 0);          // 2,359,296 B
    ushort_t* Wb    = (ushort_t*)(ws + 2359296);    // 4,718,592 B
    ushort_t* Qb    = (ushort_t*)(ws + 7077888);    // 2,359,296 B
    ushort_t* Kb    = (ushort_t*)(ws + 9437184);    // 2,359,296 B  [bh][grp][s][8]
    ushort_t* Vtb   = (ushort_t*)(ws + 11796480);   // 2,359,296 B  Vf fragment order
    ushort_t* Ctxb  = (ushort_t*)(ws + 14155776);   // 2,359,296 B
    float*    xbuf  = (float*)   (ws + 16662528);   // 4,718,592 B (end ~21.4 MB)
    // Dh/Ah (fp16 transposed-packed dist/ang) alias xbuf: written by k_convert,
    // read by k_flash, dead once k_out overwrites xbuf (stream-ordered).
    ushort_t* Dh    = (ushort_t*)(ws + 16662528);   // 2,359,296 B
    ushort_t* Ah    = (ushort_t*)(ws + 16662528 + 2359296);

    k_convert<<<4032, 256, 0, stream>>>(X, Wq, Wk, Wv, Wo, distm, angm, Xb, Wb, Dh, Ah);
    k_qkv<<<dim3(36, 24), 256, 0, stream>>>(Xb, Wb, bq, bk, bv, Qb, Kb, Vtb);
    k_flash<<<768, 256, 0, stream>>>(Qb, Kb, Vtb, Wd, bd, Wa, ba, Dh, Ah, mask, probs, Ctxb);
    k_out<<<dim3(12, 24), 256, 0, stream>>>(Ctxb, Wb + (size_t)2304 * 768, bo, X, xbuf);
    k_ln<<<1536, 256, 0, stream>>>(xbuf, ln_g, ln_b, outp);
}

// Round 9
// 179.324 us; speedup vs baseline: 1.1306x; 1.0176x over previous
//
#include <hip/hip_runtime.h>
#include <stdint.h>

#define B_  2
#define S_  768
#define D_  768
#define H_  8
#define DH_ 96

typedef unsigned short ushort_t;
typedef __bf16 bf16x8 __attribute__((ext_vector_type(8)));
typedef float  f32x4  __attribute__((ext_vector_type(4)));
typedef _Float16 f16x4 __attribute__((ext_vector_type(4)));

__device__ inline ushort_t f2bf(float f) {
    union { float f; unsigned int u; } v; v.f = f;
    unsigned int u = v.u;
    unsigned int r = u + 0x7fffu + ((u >> 16) & 1u);
    return (ushort_t)(r >> 16);
}
__device__ inline float bf2f(ushort_t u) {
    union { unsigned int i; float f; } c; c.i = ((unsigned int)u) << 16;
    return c.f;
}
__device__ inline ushort_t f2h(float f) {
    union { _Float16 h; ushort_t u; } c; c.h = (_Float16)f; return c.u;
}

// async global->LDS, 16B per lane; LDS dest is wave-uniform base + lane*16.
__device__ inline void glds16(const void* gp, void* lp) {
    auto g = reinterpret_cast<const __attribute__((address_space(1))) uint32_t*>(
        reinterpret_cast<uintptr_t>(gp));
    auto l = reinterpret_cast<__attribute__((address_space(3))) uint32_t*>(
        reinterpret_cast<uintptr_t>(lp));
    __builtin_amdgcn_global_load_lds(g, l, 16, 0, 0);
}

// counted-wait helpers (T4): raw barrier, no vmcnt(0) drain. rule #18 fences.
#define SBAR()  { __builtin_amdgcn_sched_barrier(0); __builtin_amdgcn_s_barrier(); \
                  __builtin_amdgcn_sched_barrier(0); }
#define WAIT_VM(N) { asm volatile("s_waitcnt vmcnt(" #N ")" ::: "memory"); \
                     __builtin_amdgcn_sched_barrier(0); }

// ---------------------------------------------------------------- convert
// blocks < 3456: X,Wq..Wo -> bf16 linear.
// blocks >= 3456: dist/ang -> fp16 TRANSPOSED-PACKED Dt[b][s/4][row][4] via
// LDS 64x65 tile, so k_flash's per-lane 8B reads coalesce.
__global__ __launch_bounds__(256) void k_convert(
        const float* __restrict__ X, const float* __restrict__ Wq,
        const float* __restrict__ Wk, const float* __restrict__ Wv,
        const float* __restrict__ Wo, const float* __restrict__ distm,
        const float* __restrict__ angm,
        ushort_t* __restrict__ Xb, ushort_t* __restrict__ Wb,
        ushort_t* __restrict__ Dh, ushort_t* __restrict__ Ah) {
    __shared__ float tlds[64][65];
    const int NX4 = (B_ * S_ * D_) / 4;   // 294912
    const int NW4 = (D_ * D_) / 4;        // 147456
    const int bid = blockIdx.x, tid = threadIdx.x;
    if (bid < 3456) {
        int i = bid * 256 + tid;
        float4 v;
        ushort_t* dst;
        if (i < NX4) {
            v = ((const float4*)X)[i];
            dst = Xb + i * 4;
        } else {
            int wi = i - NX4;
            int sel = wi / NW4;
            int off = wi - sel * NW4;
            const float* src = (sel == 0) ? Wq : (sel == 1) ? Wk : (sel == 2) ? Wv : Wo;
            v = ((const float4*)src)[off];
            dst = Wb + wi * 4;
        }
        ushort4 o;
        o.x = f2bf(v.x); o.y = f2bf(v.y); o.z = f2bf(v.z); o.w = f2bf(v.w);
        *(ushort4*)dst = o;
        return;
    }
    int tidx = bid - 3456;
    int mat = tidx / 288, t2 = tidx - mat * 288;
    int b = t2 / 144, t3 = t2 - b * 144;
    int rt = t3 / 12, ct = t3 - rt * 12;
    const float* src = (mat ? angm : distm) + ((size_t)(b * S_ + rt * 64)) * S_ + ct * 64;
    ushort_t* dstm = mat ? Ah : Dh;
    {
        int tr = tid >> 4, tc4 = tid & 15;
        #pragma unroll
        for (int k = 0; k < 4; ++k) {
            int row = tr + k * 16;
            float4 v4 = *(const float4*)(src + (size_t)row * S_ + tc4 * 4);
            tlds[row][tc4 * 4 + 0] = v4.x;
            tlds[row][tc4 * 4 + 1] = v4.y;
            tlds[row][tc4 * 4 + 2] = v4.z;
            tlds[row][tc4 * 4 + 3] = v4.w;
        }
    }
    __syncthreads();
    {
        int row = tid & 63, s4b = tid >> 6;
        #pragma unroll
        for (int k = 0; k < 4; ++k) {
            int s4l = s4b * 4 + k;
            ushort4 o4;
            o4.x = f2h(tlds[row][s4l * 4 + 0]);
            o4.y = f2h(tlds[row][s4l * 4 + 1]);
            o4.z = f2h(tlds[row][s4l * 4 + 2]);
            o4.w = f2h(tlds[row][s4l * 4 + 3]);
            *(ushort4*)&dstm[(((size_t)b * 192 + ct * 16 + s4l) * 768 + rt * 64 + row) * 4] = o4;
        }
    }
}

// ---------------------------------------------------------------- 64x64 GEMM, TRIPLE-buffered
// 3 LDS bufs; stage issued AFTER the barrier (targets buf i+2, whose readers
// all passed this barrier) -> ONE barrier per K-step, loads 2 tiles in flight.
__device__ inline void gemm64_tbuf(
        const ushort_t* __restrict__ A, int lda,
        const ushort_t* __restrict__ Bt, int ldb,
        int K, int m0, int n0,
        ushort_t* As, ushort_t* Bs, f32x4 acc[2][2]) {
    const int tid  = threadIdx.x;
    const int lane = tid & 63, wave = tid >> 6;
    const int wm = (wave >> 1) * 32, wn = (wave & 1) * 32;
    const int fr = lane & 15, fk = (lane >> 4) * 8;
    const ushort_t* Ap = A  + (size_t)(m0 + wave * 16 + (lane >> 2)) * lda + (lane & 3) * 8;
    const ushort_t* Bp = Bt + (size_t)(n0 + wave * 16 + (lane >> 2)) * ldb + (lane & 3) * 8;
    glds16(Ap,      As + wave * 512);
    glds16(Bp,      Bs + wave * 512);
    glds16(Ap + 32, As + 2048 + wave * 512);
    glds16(Bp + 32, Bs + 2048 + wave * 512);
    for (int kt = 0; kt < K; kt += 32) {
        const int cur = (kt >> 5) % 3;
        if (kt + 32 < K) { WAIT_VM(2) } else { WAIT_VM(0) }
        SBAR()
        if (kt + 64 < K) {
            const int nb = ((kt >> 5) + 2) % 3;
            glds16(Ap + kt + 64, As + nb * 2048 + wave * 512);
            glds16(Bp + kt + 64, Bs + nb * 2048 + wave * 512);
        }
        const ushort_t* Ab = As + cur * 2048;
        const ushort_t* Bb = Bs + cur * 2048;
        bf16x8 a0 = *(const bf16x8*)&Ab[(wm      + fr) * 32 + fk];
        bf16x8 a1 = *(const bf16x8*)&Ab[(wm + 16 + fr) * 32 + fk];
        bf16x8 b0 = *(const bf16x8*)&Bb[(wn      + fr) * 32 + fk];
        bf16x8 b1 = *(const bf16x8*)&Bb[(wn + 16 + fr) * 32 + fk];
        acc[0][0] = __builtin_amdgcn_mfma_f32_16x16x32_bf16(a0, b0, acc[0][0], 0, 0, 0);
        acc[0][1] = __builtin_amdgcn_mfma_f32_16x16x32_bf16(a0, b1, acc[0][1], 0, 0, 0);
        acc[1][0] = __builtin_amdgcn_mfma_f32_16x16x32_bf16(a1, b0, acc[1][0], 0, 0, 0);
        acc[1][1] = __builtin_amdgcn_mfma_f32_16x16x32_bf16(a1, b1, acc[1][1], 0, 0, 0);
    }
}

// ---------------------------------------------------------------- QKV GEMM (64x64, 864 blocks)
__global__ __launch_bounds__(256) void k_qkv(
        const ushort_t* __restrict__ Xb, const ushort_t* __restrict__ Wb,
        const float* __restrict__ bq, const float* __restrict__ bk,
        const float* __restrict__ bv,
        ushort_t* __restrict__ Qb, ushort_t* __restrict__ Kb,
        ushort_t* __restrict__ Vtb) {
    __shared__ __align__(16) ushort_t As[3 * 64 * 32];
    __shared__ __align__(16) ushort_t Bs[3 * 64 * 32];
    f32x4 acc[2][2];
    #pragma unroll
    for (int i = 0; i < 2; i++)
        #pragma unroll
        for (int j = 0; j < 2; j++) acc[i][j] = (f32x4){0.f, 0.f, 0.f, 0.f};
    const int m0 = blockIdx.y * 64, n0 = blockIdx.x * 64;
    gemm64_tbuf(Xb, D_, Wb, D_, D_, m0, n0, As, Bs, acc);
    const int lane = threadIdx.x & 63, wave = threadIdx.x >> 6;
    const int wm = (wave >> 1) * 32, wn = (wave & 1) * 32;
    #pragma unroll
    for (int ni = 0; ni < 2; ni++) {
        int gcol = n0 + wn + ni * 16 + (lane & 15);
        int gsel = gcol / D_, d768 = gcol - gsel * D_;
        int h = d768 / DH_, d = d768 - h * DH_;
        float bias = (gsel == 0 ? bq : (gsel == 1 ? bk : bv))[d768];
        #pragma unroll
        for (int mi = 0; mi < 2; mi++) {
            int grow0 = m0 + wm + mi * 16 + (lane >> 4) * 4;
            int b = grow0 / S_, s0 = grow0 - b * S_;
            int bh = b * H_ + h;
            if (gsel == 2) {
                ushort4 o4;
                o4.x = f2bf(acc[mi][ni][0] + bias);
                o4.y = f2bf(acc[mi][ni][1] + bias);
                o4.z = f2bf(acc[mi][ni][2] + bias);
                o4.w = f2bf(acc[mi][ni][3] + bias);
                int p = s0 >> 7, wv = (s0 >> 4) & 3, gq = (s0 >> 2) & 3;
                int e0 = (s0 >> 6) & 1;
                size_t off = ((size_t)bh * 73728) + p * 12288 + wv * 3072
                           + (d >> 4) * 512 + (gq * 16 + (d & 15)) * 8 + e0 * 4;
                *(ushort4*)&Vtb[off] = o4;
            } else if (gsel == 1) {
                #pragma unroll
                for (int r = 0; r < 4; r++)
                    Kb[(((size_t)bh * 12 + (d >> 3)) * S_ + s0 + r) * 8 + (d & 7)] =
                        f2bf(acc[mi][ni][r] + bias);
            } else {
                #pragma unroll
                for (int r = 0; r < 4; r++)
                    Qb[((size_t)bh * S_ + s0 + r) * DH_ + d] = f2bf(acc[mi][ni][r] + bias);
            }
        }
    }
}

// ---------------------------------------------------------------- fused flash v9
// v8 + (a) NON-TEMPORAL probs stores: probs (37.7MB write-once) no longer
// evicts the XCD-pinned K/V from L2; (b) manual 2-deep chunk pipeline in
// loop1 and 1-deep V-fragment pipeline in loop2 (compiler at VGPR=68 had no
// headroom to pipeline; named SSA stages force ~2 chunks in flight).
__global__ __launch_bounds__(256, 3) void k_flash(
        const ushort_t* __restrict__ Qb, const ushort_t* __restrict__ Kb,
        const ushort_t* __restrict__ Vtb,
        const float* __restrict__ Wd, const float* __restrict__ bd,
        const float* __restrict__ Wa, const float* __restrict__ ba,
        const ushort_t* __restrict__ Dh, const ushort_t* __restrict__ Ah,
        const float* __restrict__ mask,
        float* __restrict__ probs, ushort_t* __restrict__ Ctxb) {
    __shared__ float mstat[64];
    __shared__ float lstat[64];
    __shared__ float ctxred[1600];          // [16 rows][100]
    const int idx = blockIdx.x;
    const int bh = idx & 15, t = idx >> 4;  // idx%8 == h -> XCD pin
    const int b = bh >> 3, h = bh & 7;
    const int r0 = t * 16;
    const int tid = threadIdx.x, lane = tid & 63, w = tid >> 6;
    const int frn = lane & 15, g = lane >> 4;
    const ushort_t* Qbh = Qb + (size_t)bh * S_ * DH_;
    const ushort_t* Kbh = Kb + (size_t)bh * 12 * S_ * 8;   // [grp][s][8]

    #pragma unroll
    for (int i = 0; i < 7; ++i) {
        int z = tid + i * 256;
        if (z < 1600) ctxred[z] = 0.f;
    }

    // Q fragments (B operand of swapped QK^T): row = q-row = frn
    bf16x8 aq0, aq1, aq2;
    {
        const ushort_t* qp = Qbh + (size_t)(r0 + frn) * DH_ + g * 8;
        aq0 = *(const bf16x8*)qp;
        aq1 = *(const bf16x8*)(qp + 32);
        aq2 = *(const bf16x8*)(qp + 64);
    }
    // qcoef fused: lane holds q[frn][f*32+8g..+7]; reduce over g (xor 16,32)
    float qc0 = 0.f, qc1 = 0.f, qc2 = 0.f;
    #pragma unroll
    for (int f = 0; f < 3; ++f) {
        bf16x8 aq = (f == 0) ? aq0 : (f == 1) ? aq1 : aq2;
        #pragma unroll
        for (int e = 0; e < 8; ++e) {
            int d = f * 32 + g * 8 + e;
            float qv = (float)aq[e];
            qc0 += qv * Wd[d];
            qc1 += qv * Wa[d];
            qc2 += qv * (bd[d] + ba[d]);
        }
    }
    qc0 += __shfl_xor(qc0, 16); qc0 += __shfl_xor(qc0, 32);
    qc1 += __shfl_xor(qc1, 16); qc1 += __shfl_xor(qc1, 32);
    qc2 += __shfl_xor(qc2, 16); qc2 += __shfl_xor(qc2, 32);

    const float isq = 0.10206207261596577f;   // 1/sqrt(96)

    // ---- loop 1: barrier-free, dense operands, 2-deep manual pipeline
    f32x4 acc[12];
    const ushort_t* kbase = Kbh + ((size_t)g * S_ + 16 * w + frn) * 8;
    const ushort_t* dbase = Dh + ((size_t)(b * 192 + w * 4 + g) * 768 + r0 + frn) * 4;
    const ushort_t* abase = Ah + ((size_t)(b * 192 + w * 4 + g) * 768 + r0 + frn) * 4;
    const float*    mbase = mask + b * S_ + w * 16 + g * 4;
    struct Ch { bf16x8 k0, k1, k2; uint2 dd, aa; float4 m4; };
    auto LDC = [&](int c) {
        Ch r;
        const ushort_t* kp = kbase + (size_t)c * 64 * 8;
        r.k0 = *(const bf16x8*)kp;
        r.k1 = *(const bf16x8*)(kp + (size_t)4 * S_ * 8);
        r.k2 = *(const bf16x8*)(kp + (size_t)8 * S_ * 8);
        r.dd = *(const uint2*)(dbase + (size_t)c * 16 * 768 * 4);
        r.aa = *(const uint2*)(abase + (size_t)c * 16 * 768 * 4);
        r.m4 = *(const float4*)(mbase + c * 64);
        return r;
    };
    Ch p0 = LDC(0), p1 = LDC(1);
    #pragma unroll
    for (int c = 0; c < 12; ++c) {
        Ch nx;
        if (c < 10) nx = LDC(c + 2); else nx = p1;
        f32x4 ca = (f32x4){0.f, 0.f, 0.f, 0.f};
        ca = __builtin_amdgcn_mfma_f32_16x16x32_bf16(p0.k0, aq0, ca, 0, 0, 0);
        ca = __builtin_amdgcn_mfma_f32_16x16x32_bf16(p0.k1, aq1, ca, 0, 0, 0);
        ca = __builtin_amdgcn_mfma_f32_16x16x32_bf16(p0.k2, aq2, ca, 0, 0, 0);
        union { uint2 u; f16x4 hh; } dd, aa;
        dd.u = p0.dd; aa.u = p0.aa;
        f32x4 o;
        o[0] = ca[0] * isq + (float)dd.hh[0] * qc0 + (float)aa.hh[0] * qc1 + qc2 + (1.f - p0.m4.x) * -10000.f;
        o[1] = ca[1] * isq + (float)dd.hh[1] * qc0 + (float)aa.hh[1] * qc1 + qc2 + (1.f - p0.m4.y) * -10000.f;
        o[2] = ca[2] * isq + (float)dd.hh[2] * qc0 + (float)aa.hh[2] * qc1 + qc2 + (1.f - p0.m4.z) * -10000.f;
        o[3] = ca[3] * isq + (float)dd.hh[3] * qc0 + (float)aa.hh[3] * qc1 + qc2 + (1.f - p0.m4.w) * -10000.f;
        acc[c] = o;
        p0 = p1; p1 = nx;
    }

    // ---- softmax (exact; q-row = frn lane-local; 2 barriers)
    float mx = -1e30f;
    #pragma unroll
    for (int c = 0; c < 12; ++c)
        #pragma unroll
        for (int r = 0; r < 4; ++r) mx = fmaxf(mx, acc[c][r]);
    mx = fmaxf(mx, __shfl_xor(mx, 16));
    mx = fmaxf(mx, __shfl_xor(mx, 32));
    if (g == 0) mstat[w * 16 + frn] = mx;
    __syncthreads();
    float mf = fmaxf(fmaxf(mstat[frn], mstat[16 + frn]),
                     fmaxf(mstat[32 + frn], mstat[48 + frn]));
    float sum = 0.f;
    #pragma unroll
    for (int c = 0; c < 12; ++c)
        #pragma unroll
        for (int r = 0; r < 4; ++r) {
            float e = __expf(acc[c][r] - mf);
            acc[c][r] = e;
            sum += e;
        }
    sum += __shfl_xor(sum, 16);
    sum += __shfl_xor(sum, 32);
    if (g == 0) lstat[w * 16 + frn] = sum;
    __syncthreads();
    float inv = 1.f / (lstat[frn] + lstat[16 + frn] + lstat[32 + frn] + lstat[48 + frn]);

    // ---- loop 2: probs NT from regs; V fragment-dense, 1-deep pipeline
    f32x4 accO[6];
    #pragma unroll
    for (int i = 0; i < 6; ++i) accO[i] = (f32x4){0.f, 0.f, 0.f, 0.f};
    float* prow = probs + ((size_t)bh * S_ + r0 + frn) * S_ + w * 16 + g * 4;
    const ushort_t* vfb = Vtb + (size_t)bh * 73728 + w * 3072 + lane * 8;
    bf16x8 vcur[6];
    #pragma unroll
    for (int nt = 0; nt < 6; ++nt)
        vcur[nt] = *(const bf16x8*)(vfb + nt * 512);
    #pragma unroll
    for (int p = 0; p < 6; ++p) {
        const int c = 2 * p;
        bf16x8 vnx[6];
        #pragma unroll
        for (int nt = 0; nt < 6; ++nt)
            vnx[nt] = (p < 5) ? *(const bf16x8*)(vfb + (p + 1) * 12288 + nt * 512)
                              : vcur[nt];
        f32x4 pw;
        pw[0] = acc[c][0] * inv; pw[1] = acc[c][1] * inv;
        pw[2] = acc[c][2] * inv; pw[3] = acc[c][3] * inv;
        __builtin_nontemporal_store(pw, (f32x4*)(prow + c * 64));
        pw[0] = acc[c + 1][0] * inv; pw[1] = acc[c + 1][1] * inv;
        pw[2] = acc[c + 1][2] * inv; pw[3] = acc[c + 1][3] * inv;
        __builtin_nontemporal_store(pw, (f32x4*)(prow + (c + 1) * 64));
        union { bf16x8 v; ushort_t u[8]; } pa;
        #pragma unroll
        for (int r = 0; r < 4; ++r) {
            pa.u[r]     = f2bf(acc[c][r]);
            pa.u[r + 4] = f2bf(acc[c + 1][r]);
        }
        #pragma unroll
        for (int nt = 0; nt < 6; ++nt)
            accO[nt] = __builtin_amdgcn_mfma_f32_16x16x32_bf16(pa.v, vcur[nt], accO[nt], 0, 0, 0);
        #pragma unroll
        for (int nt = 0; nt < 6; ++nt) vcur[nt] = vnx[nt];
    }

    // ---- cross-wave reduce (kappa-slice partials) + ctx write (1 barrier)
    #pragma unroll
    for (int nt = 0; nt < 6; ++nt)
        #pragma unroll
        for (int r = 0; r < 4; ++r)
            atomicAdd(&ctxred[(4 * g + r) * 100 + nt * 16 + frn], accO[nt][r]);
    __syncthreads();
    {
        int zr = tid >> 4, zc = tid & 15;
        float ivr = 1.f / (lstat[zr] + lstat[16 + zr] + lstat[32 + zr] + lstat[48 + zr]);
        ushort_t* crow = Ctxb + ((size_t)b * S_ + r0 + zr) * D_ + h * DH_;
        #pragma unroll
        for (int i = 0; i < 6; ++i)
            crow[i * 16 + zc] = f2bf(ctxred[zr * 100 + i * 16 + zc] * ivr);
    }
}

// ---------------------------------------------------------------- out GEMM + bias + residual
__global__ __launch_bounds__(256) void k_out(
        const ushort_t* __restrict__ Ctxb, const ushort_t* __restrict__ Wob,
        const float* __restrict__ bo, const float* __restrict__ hidden,
        float* __restrict__ xbuf) {
    __shared__ __align__(16) ushort_t As[3 * 64 * 32];
    __shared__ __align__(16) ushort_t Bs[3 * 64 * 32];
    f32x4 acc[2][2];
    #pragma unroll
    for (int i = 0; i < 2; i++)
        #pragma unroll
        for (int j = 0; j < 2; j++) acc[i][j] = (f32x4){0.f, 0.f, 0.f, 0.f};
    const int m0 = blockIdx.y * 64, n0 = blockIdx.x * 64;
    gemm64_tbuf(Ctxb, D_, Wob, D_, D_, m0, n0, As, Bs, acc);
    const int lane = threadIdx.x & 63, wave = threadIdx.x >> 6;
    const int wm = (wave >> 1) * 32, wn = (wave & 1) * 32;
    #pragma unroll
    for (int ni = 0; ni < 2; ni++) {
        int gcol = n0 + wn + ni * 16 + (lane & 15);
        float bias = bo[gcol];
        #pragma unroll
        for (int mi = 0; mi < 2; mi++) {
            #pragma unroll
            for (int r = 0; r < 4; r++) {
                int grow = m0 + wm + mi * 16 + (lane >> 4) * 4 + r;
                xbuf[(size_t)grow * D_ + gcol] =
                    acc[mi][ni][r] + bias + hidden[(size_t)grow * D_ + gcol];
            }
        }
    }
}

// ---------------------------------------------------------------- LayerNorm
__global__ __launch_bounds__(256) void k_ln(
        const float* __restrict__ xbuf, const float* __restrict__ g,
        const float* __restrict__ bb, float* __restrict__ out) {
    const float* x = xbuf + (size_t)blockIdx.x * D_;
    const int t = threadIdx.x;
    float a0 = x[t], a1 = x[t + 256], a2 = x[t + 512];
    float s = a0 + a1 + a2;
    float ss = a0 * a0 + a1 * a1 + a2 * a2;
    __shared__ float r1[4], r2[4];
    #pragma unroll
    for (int o = 32; o > 0; o >>= 1) { s += __shfl_down(s, o); ss += __shfl_down(ss, o); }
    if ((t & 63) == 0) { r1[t >> 6] = s; r2[t >> 6] = ss; }
    __syncthreads();
    float ts = r1[0] + r1[1] + r1[2] + r1[3];
    float tss = r2[0] + r2[1] + r2[2] + r2[3];
    float mu = ts * (1.0f / D_);
    float var = tss * (1.0f / D_) - mu * mu;
    float rstd = rsqrtf(var + 1e-5f);
    float* o = out + (size_t)blockIdx.x * D_;
    o[t]       = (a0 - mu) * rstd * g[t]       + bb[t];
    o[t + 256] = (a1 - mu) * rstd * g[t + 256] + bb[t + 256];
    o[t + 512] = (a2 - mu) * rstd * g[t + 512] + bb[t + 512];
}

// ---------------------------------------------------------------- launch
extern "C" void kernel_launch(void* const* d_in, const int* in_sizes, int n_in,
                              void* d_out, int out_size, void* d_ws, size_t ws_size,
                              hipStream_t stream) {
    const float* X     = (const float*)d_in[0];
    const float* distm = (const float*)d_in[1];
    const float* angm  = (const float*)d_in[2];
    const float* mask  = (const float*)d_in[3];
    const float* Wq    = (const float*)d_in[4];
    const float* bq    = (const float*)d_in[5];
    const float* Wk    = (const float*)d_in[6];
    const float* bk    = (const float*)d_in[7];
    const float* Wv    = (const float*)d_in[8];
    const float* bv    = (const float*)d_in[9];
    const float* Wd    = (const float*)d_in[10];
    const float* bd    = (const float*)d_in[11];
    const float* Wa    = (const float*)d_in[12];
    const float* ba    = (const float*)d_in[13];
    const float* Wo    = (const float*)d_in[14];
    const float* bo    = (const float*)d_in[15];
    const float* ln_g  = (const float*)d_in[16];
    const float* ln_b  = (const float*)d_in[17];

    float* outp  = (float*)d_out;                        // [B,S,D]
    float* probs = (float*)d_out + (size_t)B_ * S_ * D_; // [B,H,S,S]

    char* ws = (char*)d_ws;
    ushort_t* Xb    = (ushort_t*)(ws + 0);          // 2,359,296 B
    ushort_t* Wb    = (ushort_t*)(ws + 2359296);    // 4,718,592 B
    ushort_t* Qb    = (ushort_t*)(ws + 7077888);    // 2,359,296 B
    ushort_t* Kb    = (ushort_t*)(ws + 9437184);    // 2,359,296 B  [bh][grp][s][8]
    ushort_t* Vtb   = (ushort_t*)(ws + 11796480);   // 2,359,296 B  Vf fragment order
    ushort_t* Ctxb  = (ushort_t*)(ws + 14155776);   // 2,359,296 B
    float*    xbuf  = (float*)   (ws + 16662528);   // 4,718,592 B (end ~21.4 MB)
    // Dh/Ah (fp16 transposed-packed dist/ang) alias xbuf: written by k_convert,
    // read by k_flash, dead once k_out overwrites xbuf (stream-ordered).
    ushort_t* Dh    = (ushort_t*)(ws + 16662528);   // 2,359,296 B
    ushort_t* Ah    = (ushort_t*)(ws + 16662528 + 2359296);

    k_convert<<<4032, 256, 0, stream>>>(X, Wq, Wk, Wv, Wo, distm, angm, Xb, Wb, Dh, Ah);
    k_qkv<<<dim3(36, 24), 256, 0, stream>>>(Xb, Wb, bq, bk, bv, Qb, Kb, Vtb);
    k_flash<<<768, 256, 0, stream>>>(Qb, Kb, Vtb, Wd, bd, Wa, ba, Dh, Ah, mask, probs, Ctxb);
    k_out<<<dim3(12, 24), 256, 0, stream>>>(Ctxb, Wb + (size_t)2304 * 768, bo, X, xbuf);
    k_ln<<<1536, 256, 0, stream>>>(xbuf, ln_g, ln_b, outp);
}

// Round 10
// 174.715 us; speedup vs baseline: 1.1605x; 1.0264x over previous
//
#include <hip/hip_runtime.h>
#include <stdint.h>

#define B_  2
#define S_  768
#define D_  768
#define H_  8
#define DH_ 96

typedef unsigned short ushort_t;
typedef __bf16 bf16x8 __attribute__((ext_vector_type(8)));
typedef float  f32x4  __attribute__((ext_vector_type(4)));
typedef _Float16 f16x4 __attribute__((ext_vector_type(4)));

__device__ inline ushort_t f2bf(float f) {
    union { float f; unsigned int u; } v; v.f = f;
    unsigned int u = v.u;
    unsigned int r = u + 0x7fffu + ((u >> 16) & 1u);
    return (ushort_t)(r >> 16);
}
__device__ inline float bf2f(ushort_t u) {
    union { unsigned int i; float f; } c; c.i = ((unsigned int)u) << 16;
    return c.f;
}
__device__ inline ushort_t f2h(float f) {
    union { _Float16 h; ushort_t u; } c; c.h = (_Float16)f; return c.u;
}

// async global->LDS, 16B per lane; LDS dest is wave-uniform base + lane*16.
__device__ inline void glds16(const void* gp, void* lp) {
    auto g = reinterpret_cast<const __attribute__((address_space(1))) uint32_t*>(
        reinterpret_cast<uintptr_t>(gp));
    auto l = reinterpret_cast<__attribute__((address_space(3))) uint32_t*>(
        reinterpret_cast<uintptr_t>(lp));
    __builtin_amdgcn_global_load_lds(g, l, 16, 0, 0);
}

// counted-wait helpers (T4): raw barrier, no vmcnt(0) drain. rule #18 fences.
#define SBAR()  { __builtin_amdgcn_sched_barrier(0); __builtin_amdgcn_s_barrier(); \
                  __builtin_amdgcn_sched_barrier(0); }
#define WAIT_VM(N) { asm volatile("s_waitcnt vmcnt(" #N ")" ::: "memory"); \
                     __builtin_amdgcn_sched_barrier(0); }

// ---------------------------------------------------------------- convert (X, weights only)
__global__ __launch_bounds__(256) void k_convert(
        const float* __restrict__ X, const float* __restrict__ Wq,
        const float* __restrict__ Wk, const float* __restrict__ Wv,
        const float* __restrict__ Wo,
        ushort_t* __restrict__ Xb, ushort_t* __restrict__ Wb) {
    const int NX4 = (B_ * S_ * D_) / 4;   // 294912
    const int NW4 = (D_ * D_) / 4;        // 147456
    int i = blockIdx.x * 256 + threadIdx.x;
    float4 v;
    ushort_t* dst;
    if (i < NX4) {
        v = ((const float4*)X)[i];
        dst = Xb + i * 4;
    } else {
        int wi = i - NX4;
        int sel = wi / NW4;
        int off = wi - sel * NW4;
        const float* src = (sel == 0) ? Wq : (sel == 1) ? Wk : (sel == 2) ? Wv : Wo;
        v = ((const float4*)src)[off];
        dst = Wb + wi * 4;
    }
    ushort4 o;
    o.x = f2bf(v.x); o.y = f2bf(v.y); o.z = f2bf(v.z); o.w = f2bf(v.w);
    *(ushort4*)dst = o;
}

// ---------------------------------------------------------------- QKV GEMM 128x128 @512thr
// bid < 216: GEMM C = Xb[1536,768] x Wb[2304,768]^T, 128x128 tile, 8 waves
// (2x4), triple-buffered glds staging, ONE barrier per K-step, loads 2 tiles
// in flight (stage issued AFTER the barrier targets buf i+2 whose readers all
// passed this barrier). Traffic 204->85 MB vs 64^2 tile.
// bid >= 216: dist/ang fp16 transpose-pack tiles (no dependence on Xb/Wb ->
// runs concurrently with the GEMM; removes the serial pre-pass + one launch).
__global__ __launch_bounds__(512) void k_qkvt(
        const ushort_t* __restrict__ Xb, const ushort_t* __restrict__ Wb,
        const float* __restrict__ bq, const float* __restrict__ bk,
        const float* __restrict__ bv,
        const float* __restrict__ distm, const float* __restrict__ angm,
        ushort_t* __restrict__ Qb, ushort_t* __restrict__ Kb,
        ushort_t* __restrict__ Vtb,
        ushort_t* __restrict__ Dh, ushort_t* __restrict__ Ah) {
    __shared__ __align__(16) char sm[49152];   // 3 bufs x (A 8K + B 8K)
    const int bid = blockIdx.x, tid = threadIdx.x;
    if (bid >= 216) {
        // ---- dist/ang transpose: 576 blocks = 2 mats x 2 b x 12 rt x 12 ct
        float* tlds = (float*)sm;               // [64][65]
        int tidx = bid - 216;
        int mat = tidx / 288, t2 = tidx - mat * 288;
        int b = t2 / 144, t3 = t2 - b * 144;
        int rt = t3 / 12, ct = t3 - rt * 12;
        const float* src = (mat ? angm : distm) + ((size_t)(b * S_ + rt * 64)) * S_ + ct * 64;
        ushort_t* dstm = mat ? Ah : Dh;
        {
            int tr = tid >> 4, tc4 = tid & 15;
            #pragma unroll
            for (int k = 0; k < 2; ++k) {
                int row = tr + k * 32;
                float4 v4 = *(const float4*)(src + (size_t)row * S_ + tc4 * 4);
                tlds[row * 65 + tc4 * 4 + 0] = v4.x;
                tlds[row * 65 + tc4 * 4 + 1] = v4.y;
                tlds[row * 65 + tc4 * 4 + 2] = v4.z;
                tlds[row * 65 + tc4 * 4 + 3] = v4.w;
            }
        }
        __syncthreads();
        {
            int row = tid & 63, s4b = tid >> 6;
            #pragma unroll
            for (int k = 0; k < 2; ++k) {
                int s4l = s4b * 2 + k;
                ushort4 o4;
                o4.x = f2h(tlds[row * 65 + s4l * 4 + 0]);
                o4.y = f2h(tlds[row * 65 + s4l * 4 + 1]);
                o4.z = f2h(tlds[row * 65 + s4l * 4 + 2]);
                o4.w = f2h(tlds[row * 65 + s4l * 4 + 3]);
                *(ushort4*)&dstm[(((size_t)b * 192 + ct * 16 + s4l) * 768 + rt * 64 + row) * 4] = o4;
            }
        }
        return;
    }
    // ---- GEMM: by = bid/18, bx = bid%18
    ushort_t* As = (ushort_t*)sm;               // [3][128*32]
    ushort_t* Bs = (ushort_t*)(sm + 24576);     // [3][128*32]
    const int by = bid / 18, bx = bid - by * 18;
    const int m0 = by * 128, n0 = bx * 128;
    const int lane = tid & 63, w = tid >> 6;
    const int wr = w >> 2, wc = w & 3;
    const int wm = wr * 64, wn = wc * 32;
    const int frn = lane & 15, fko = (lane >> 4) * 8, frg4 = (lane >> 4) * 4;
    const ushort_t* Ap = Xb + (size_t)(m0 + w * 16 + (lane >> 2)) * D_ + (lane & 3) * 8;
    const ushort_t* Bp = Wb + (size_t)(n0 + w * 16 + (lane >> 2)) * D_ + (lane & 3) * 8;
    f32x4 acc[4][2];
    #pragma unroll
    for (int i = 0; i < 4; ++i)
        #pragma unroll
        for (int j = 0; j < 2; ++j) acc[i][j] = (f32x4){0.f, 0.f, 0.f, 0.f};
    glds16(Ap,      As + w * 512);
    glds16(Bp,      Bs + w * 512);
    glds16(Ap + 32, As + 4096 + w * 512);
    glds16(Bp + 32, Bs + 4096 + w * 512);
    for (int kt = 0; kt < D_; kt += 32) {
        const int cur = (kt >> 5) % 3;
        if (kt + 32 < D_) { WAIT_VM(2) } else { WAIT_VM(0) }
        SBAR()
        if (kt + 64 < D_) {
            const int nb = ((kt >> 5) + 2) % 3;
            glds16(Ap + kt + 64, As + nb * 4096 + w * 512);
            glds16(Bp + kt + 64, Bs + nb * 4096 + w * 512);
        }
        const ushort_t* Ab = As + cur * 4096;
        const ushort_t* Bb = Bs + cur * 4096;
        bf16x8 af[4], bfr[2];
        #pragma unroll
        for (int i = 0; i < 4; ++i)
            af[i] = *(const bf16x8*)&Ab[(wm + i * 16 + frn) * 32 + fko];
        #pragma unroll
        for (int j = 0; j < 2; ++j)
            bfr[j] = *(const bf16x8*)&Bb[(wn + j * 16 + frn) * 32 + fko];
        #pragma unroll
        for (int i = 0; i < 4; ++i)
            #pragma unroll
            for (int j = 0; j < 2; ++j)
                acc[i][j] = __builtin_amdgcn_mfma_f32_16x16x32_bf16(af[i], bfr[j], acc[i][j], 0, 0, 0);
    }
    #pragma unroll
    for (int j = 0; j < 2; ++j) {
        int gcol = n0 + wn + j * 16 + frn;
        int gsel = gcol / D_, d768 = gcol - gsel * D_;
        int h = d768 / DH_, d = d768 - h * DH_;
        float bias = (gsel == 0 ? bq : (gsel == 1 ? bk : bv))[d768];
        #pragma unroll
        for (int i = 0; i < 4; ++i) {
            int grow0 = m0 + wm + i * 16 + frg4;
            int b = grow0 / S_, s0 = grow0 - b * S_;
            int bh = b * H_ + h;
            if (gsel == 2) {
                ushort4 o4;
                o4.x = f2bf(acc[i][j][0] + bias);
                o4.y = f2bf(acc[i][j][1] + bias);
                o4.z = f2bf(acc[i][j][2] + bias);
                o4.w = f2bf(acc[i][j][3] + bias);
                int p = s0 >> 7, wv = (s0 >> 4) & 3, gq = (s0 >> 2) & 3;
                int e0 = (s0 >> 6) & 1;
                size_t off = ((size_t)bh * 73728) + p * 12288 + wv * 3072
                           + (d >> 4) * 512 + (gq * 16 + (d & 15)) * 8 + e0 * 4;
                *(ushort4*)&Vtb[off] = o4;
            } else if (gsel == 1) {
                #pragma unroll
                for (int r = 0; r < 4; r++)
                    Kb[(((size_t)bh * 12 + (d >> 3)) * S_ + s0 + r) * 8 + (d & 7)] =
                        f2bf(acc[i][j][r] + bias);
            } else {
                #pragma unroll
                for (int r = 0; r < 4; r++)
                    Qb[((size_t)bh * S_ + s0 + r) * DH_ + d] = f2bf(acc[i][j][r] + bias);
            }
        }
    }
}

// ---------------------------------------------------------------- 64x64 GEMM, TRIPLE-buffered
__device__ inline void gemm64_tbuf(
        const ushort_t* __restrict__ A, int lda,
        const ushort_t* __restrict__ Bt, int ldb,
        int K, int m0, int n0,
        ushort_t* As, ushort_t* Bs, f32x4 acc[2][2]) {
    const int tid  = threadIdx.x;
    const int lane = tid & 63, wave = tid >> 6;
    const int wm = (wave >> 1) * 32, wn = (wave & 1) * 32;
    const int fr = lane & 15, fk = (lane >> 4) * 8;
    const ushort_t* Ap = A  + (size_t)(m0 + wave * 16 + (lane >> 2)) * lda + (lane & 3) * 8;
    const ushort_t* Bp = Bt + (size_t)(n0 + wave * 16 + (lane >> 2)) * ldb + (lane & 3) * 8;
    glds16(Ap,      As + wave * 512);
    glds16(Bp,      Bs + wave * 512);
    glds16(Ap + 32, As + 2048 + wave * 512);
    glds16(Bp + 32, Bs + 2048 + wave * 512);
    for (int kt = 0; kt < K; kt += 32) {
        const int cur = (kt >> 5) % 3;
        if (kt + 32 < K) { WAIT_VM(2) } else { WAIT_VM(0) }
        SBAR()
        if (kt + 64 < K) {
            const int nb = ((kt >> 5) + 2) % 3;
            glds16(Ap + kt + 64, As + nb * 2048 + wave * 512);
            glds16(Bp + kt + 64, Bs + nb * 2048 + wave * 512);
        }
        const ushort_t* Ab = As + cur * 2048;
        const ushort_t* Bb = Bs + cur * 2048;
        bf16x8 a0 = *(const bf16x8*)&Ab[(wm      + fr) * 32 + fk];
        bf16x8 a1 = *(const bf16x8*)&Ab[(wm + 16 + fr) * 32 + fk];
        bf16x8 b0 = *(const bf16x8*)&Bb[(wn      + fr) * 32 + fk];
        bf16x8 b1 = *(const bf16x8*)&Bb[(wn + 16 + fr) * 32 + fk];
        acc[0][0] = __builtin_amdgcn_mfma_f32_16x16x32_bf16(a0, b0, acc[0][0], 0, 0, 0);
        acc[0][1] = __builtin_amdgcn_mfma_f32_16x16x32_bf16(a0, b1, acc[0][1], 0, 0, 0);
        acc[1][0] = __builtin_amdgcn_mfma_f32_16x16x32_bf16(a1, b0, acc[1][0], 0, 0, 0);
        acc[1][1] = __builtin_amdgcn_mfma_f32_16x16x32_bf16(a1, b1, acc[1][1], 0, 0, 0);
    }
}

// ---------------------------------------------------------------- fused flash v9 (unchanged)
__global__ __launch_bounds__(256, 3) void k_flash(
        const ushort_t* __restrict__ Qb, const ushort_t* __restrict__ Kb,
        const ushort_t* __restrict__ Vtb,
        const float* __restrict__ Wd, const float* __restrict__ bd,
        const float* __restrict__ Wa, const float* __restrict__ ba,
        const ushort_t* __restrict__ Dh, const ushort_t* __restrict__ Ah,
        const float* __restrict__ mask,
        float* __restrict__ probs, ushort_t* __restrict__ Ctxb) {
    __shared__ float mstat[64];
    __shared__ float lstat[64];
    __shared__ float ctxred[1600];          // [16 rows][100]
    const int idx = blockIdx.x;
    const int bh = idx & 15, t = idx >> 4;  // idx%8 == h -> XCD pin
    const int b = bh >> 3, h = bh & 7;
    const int r0 = t * 16;
    const int tid = threadIdx.x, lane = tid & 63, w = tid >> 6;
    const int frn = lane & 15, g = lane >> 4;
    const ushort_t* Qbh = Qb + (size_t)bh * S_ * DH_;
    const ushort_t* Kbh = Kb + (size_t)bh * 12 * S_ * 8;   // [grp][s][8]

    #pragma unroll
    for (int i = 0; i < 7; ++i) {
        int z = tid + i * 256;
        if (z < 1600) ctxred[z] = 0.f;
    }

    bf16x8 aq0, aq1, aq2;
    {
        const ushort_t* qp = Qbh + (size_t)(r0 + frn) * DH_ + g * 8;
        aq0 = *(const bf16x8*)qp;
        aq1 = *(const bf16x8*)(qp + 32);
        aq2 = *(const bf16x8*)(qp + 64);
    }
    float qc0 = 0.f, qc1 = 0.f, qc2 = 0.f;
    #pragma unroll
    for (int f = 0; f < 3; ++f) {
        bf16x8 aq = (f == 0) ? aq0 : (f == 1) ? aq1 : aq2;
        #pragma unroll
        for (int e = 0; e < 8; ++e) {
            int d = f * 32 + g * 8 + e;
            float qv = (float)aq[e];
            qc0 += qv * Wd[d];
            qc1 += qv * Wa[d];
            qc2 += qv * (bd[d] + ba[d]);
        }
    }
    qc0 += __shfl_xor(qc0, 16); qc0 += __shfl_xor(qc0, 32);
    qc1 += __shfl_xor(qc1, 16); qc1 += __shfl_xor(qc1, 32);
    qc2 += __shfl_xor(qc2, 16); qc2 += __shfl_xor(qc2, 32);

    const float isq = 0.10206207261596577f;   // 1/sqrt(96)

    f32x4 acc[12];
    const ushort_t* kbase = Kbh + ((size_t)g * S_ + 16 * w + frn) * 8;
    const ushort_t* dbase = Dh + ((size_t)(b * 192 + w * 4 + g) * 768 + r0 + frn) * 4;
    const ushort_t* abase = Ah + ((size_t)(b * 192 + w * 4 + g) * 768 + r0 + frn) * 4;
    const float*    mbase = mask + b * S_ + w * 16 + g * 4;
    struct Ch { bf16x8 k0, k1, k2; uint2 dd, aa; float4 m4; };
    auto LDC = [&](int c) {
        Ch r;
        const ushort_t* kp = kbase + (size_t)c * 64 * 8;
        r.k0 = *(const bf16x8*)kp;
        r.k1 = *(const bf16x8*)(kp + (size_t)4 * S_ * 8);
        r.k2 = *(const bf16x8*)(kp + (size_t)8 * S_ * 8);
        r.dd = *(const uint2*)(dbase + (size_t)c * 16 * 768 * 4);
        r.aa = *(const uint2*)(abase + (size_t)c * 16 * 768 * 4);
        r.m4 = *(const float4*)(mbase + c * 64);
        return r;
    };
    Ch p0 = LDC(0), p1 = LDC(1);
    #pragma unroll
    for (int c = 0; c < 12; ++c) {
        Ch nx;
        if (c < 10) nx = LDC(c + 2); else nx = p1;
        f32x4 ca = (f32x4){0.f, 0.f, 0.f, 0.f};
        ca = __builtin_amdgcn_mfma_f32_16x16x32_bf16(p0.k0, aq0, ca, 0, 0, 0);
        ca = __builtin_amdgcn_mfma_f32_16x16x32_bf16(p0.k1, aq1, ca, 0, 0, 0);
        ca = __builtin_amdgcn_mfma_f32_16x16x32_bf16(p0.k2, aq2, ca, 0, 0, 0);
        union { uint2 u; f16x4 hh; } dd, aa;
        dd.u = p0.dd; aa.u = p0.aa;
        f32x4 o;
        o[0] = ca[0] * isq + (float)dd.hh[0] * qc0 + (float)aa.hh[0] * qc1 + qc2 + (1.f - p0.m4.x) * -10000.f;
        o[1] = ca[1] * isq + (float)dd.hh[1] * qc0 + (float)aa.hh[1] * qc1 + qc2 + (1.f - p0.m4.y) * -10000.f;
        o[2] = ca[2] * isq + (float)dd.hh[2] * qc0 + (float)aa.hh[2] * qc1 + qc2 + (1.f - p0.m4.z) * -10000.f;
        o[3] = ca[3] * isq + (float)dd.hh[3] * qc0 + (float)aa.hh[3] * qc1 + qc2 + (1.f - p0.m4.w) * -10000.f;
        acc[c] = o;
        p0 = p1; p1 = nx;
    }

    float mx = -1e30f;
    #pragma unroll
    for (int c = 0; c < 12; ++c)
        #pragma unroll
        for (int r = 0; r < 4; ++r) mx = fmaxf(mx, acc[c][r]);
    mx = fmaxf(mx, __shfl_xor(mx, 16));
    mx = fmaxf(mx, __shfl_xor(mx, 32));
    if (g == 0) mstat[w * 16 + frn] = mx;
    __syncthreads();
    float mf = fmaxf(fmaxf(mstat[frn], mstat[16 + frn]),
                     fmaxf(mstat[32 + frn], mstat[48 + frn]));
    float sum = 0.f;
    #pragma unroll
    for (int c = 0; c < 12; ++c)
        #pragma unroll
        for (int r = 0; r < 4; ++r) {
            float e = __expf(acc[c][r] - mf);
            acc[c][r] = e;
            sum += e;
        }
    sum += __shfl_xor(sum, 16);
    sum += __shfl_xor(sum, 32);
    if (g == 0) lstat[w * 16 + frn] = sum;
    __syncthreads();
    float inv = 1.f / (lstat[frn] + lstat[16 + frn] + lstat[32 + frn] + lstat[48 + frn]);

    f32x4 accO[6];
    #pragma unroll
    for (int i = 0; i < 6; ++i) accO[i] = (f32x4){0.f, 0.f, 0.f, 0.f};
    float* prow = probs + ((size_t)bh * S_ + r0 + frn) * S_ + w * 16 + g * 4;
    const ushort_t* vfb = Vtb + (size_t)bh * 73728 + w * 3072 + lane * 8;
    bf16x8 vcur[6];
    #pragma unroll
    for (int nt = 0; nt < 6; ++nt)
        vcur[nt] = *(const bf16x8*)(vfb + nt * 512);
    #pragma unroll
    for (int p = 0; p < 6; ++p) {
        const int c = 2 * p;
        bf16x8 vnx[6];
        #pragma unroll
        for (int nt = 0; nt < 6; ++nt)
            vnx[nt] = (p < 5) ? *(const bf16x8*)(vfb + (p + 1) * 12288 + nt * 512)
                              : vcur[nt];
        f32x4 pw;
        pw[0] = acc[c][0] * inv; pw[1] = acc[c][1] * inv;
        pw[2] = acc[c][2] * inv; pw[3] = acc[c][3] * inv;
        __builtin_nontemporal_store(pw, (f32x4*)(prow + c * 64));
        pw[0] = acc[c + 1][0] * inv; pw[1] = acc[c + 1][1] * inv;
        pw[2] = acc[c + 1][2] * inv; pw[3] = acc[c + 1][3] * inv;
        __builtin_nontemporal_store(pw, (f32x4*)(prow + (c + 1) * 64));
        union { bf16x8 v; ushort_t u[8]; } pa;
        #pragma unroll
        for (int r = 0; r < 4; ++r) {
            pa.u[r]     = f2bf(acc[c][r]);
            pa.u[r + 4] = f2bf(acc[c + 1][r]);
        }
        #pragma unroll
        for (int nt = 0; nt < 6; ++nt)
            accO[nt] = __builtin_amdgcn_mfma_f32_16x16x32_bf16(pa.v, vcur[nt], accO[nt], 0, 0, 0);
        #pragma unroll
        for (int nt = 0; nt < 6; ++nt) vcur[nt] = vnx[nt];
    }

    #pragma unroll
    for (int nt = 0; nt < 6; ++nt)
        #pragma unroll
        for (int r = 0; r < 4; ++r)
            atomicAdd(&ctxred[(4 * g + r) * 100 + nt * 16 + frn], accO[nt][r]);
    __syncthreads();
    {
        int zr = tid >> 4, zc = tid & 15;
        float ivr = 1.f / (lstat[zr] + lstat[16 + zr] + lstat[32 + zr] + lstat[48 + zr]);
        ushort_t* crow = Ctxb + ((size_t)b * S_ + r0 + zr) * D_ + h * DH_;
        #pragma unroll
        for (int i = 0; i < 6; ++i)
            crow[i * 16 + zc] = f2bf(ctxred[zr * 100 + i * 16 + zc] * ivr);
    }
}

// ---------------------------------------------------------------- out GEMM + bias + residual
__global__ __launch_bounds__(256) void k_out(
        const ushort_t* __restrict__ Ctxb, const ushort_t* __restrict__ Wob,
        const float* __restrict__ bo, const float* __restrict__ hidden,
        float* __restrict__ xbuf) {
    __shared__ __align__(16) ushort_t As[3 * 64 * 32];
    __shared__ __align__(16) ushort_t Bs[3 * 64 * 32];
    f32x4 acc[2][2];
    #pragma unroll
    for (int i = 0; i < 2; i++)
        #pragma unroll
        for (int j = 0; j < 2; j++) acc[i][j] = (f32x4){0.f, 0.f, 0.f, 0.f};
    const int m0 = blockIdx.y * 64, n0 = blockIdx.x * 64;
    gemm64_tbuf(Ctxb, D_, Wob, D_, D_, m0, n0, As, Bs, acc);
    const int lane = threadIdx.x & 63, wave = threadIdx.x >> 6;
    const int wm = (wave >> 1) * 32, wn = (wave & 1) * 32;
    #pragma unroll
    for (int ni = 0; ni < 2; ni++) {
        int gcol = n0 + wn + ni * 16 + (lane & 15);
        float bias = bo[gcol];
        #pragma unroll
        for (int mi = 0; mi < 2; mi++) {
            #pragma unroll
            for (int r = 0; r < 4; r++) {
                int grow = m0 + wm + mi * 16 + (lane >> 4) * 4 + r;
                xbuf[(size_t)grow * D_ + gcol] =
                    acc[mi][ni][r] + bias + hidden[(size_t)grow * D_ + gcol];
            }
        }
    }
}

// ---------------------------------------------------------------- LayerNorm
__global__ __launch_bounds__(256) void k_ln(
        const float* __restrict__ xbuf, const float* __restrict__ g,
        const float* __restrict__ bb, float* __restrict__ out) {
    const float* x = xbuf + (size_t)blockIdx.x * D_;
    const int t = threadIdx.x;
    float a0 = x[t], a1 = x[t + 256], a2 = x[t + 512];
    float s = a0 + a1 + a2;
    float ss = a0 * a0 + a1 * a1 + a2 * a2;
    __shared__ float r1[4], r2[4];
    #pragma unroll
    for (int o = 32; o > 0; o >>= 1) { s += __shfl_down(s, o); ss += __shfl_down(ss, o); }
    if ((t & 63) == 0) { r1[t >> 6] = s; r2[t >> 6] = ss; }
    __syncthreads();
    float ts = r1[0] + r1[1] + r1[2] + r1[3];
    float tss = r2[0] + r2[1] + r2[2] + r2[3];
    float mu = ts * (1.0f / D_);
    float var = tss * (1.0f / D_) - mu * mu;
    float rstd = rsqrtf(var + 1e-5f);
    float* o = out + (size_t)blockIdx.x * D_;
    o[t]       = (a0 - mu) * rstd * g[t]       + bb[t];
    o[t + 256] = (a1 - mu) * rstd * g[t + 256] + bb[t + 256];
    o[t + 512] = (a2 - mu) * rstd * g[t + 512] + bb[t + 512];
}

// ---------------------------------------------------------------- launch
extern "C" void kernel_launch(void* const* d_in, const int* in_sizes, int n_in,
                              void* d_out, int out_size, void* d_ws, size_t ws_size,
                              hipStream_t stream) {
    const float* X     = (const float*)d_in[0];
    const float* distm = (const float*)d_in[1];
    const float* angm  = (const float*)d_in[2];
    const float* mask  = (const float*)d_in[3];
    const float* Wq    = (const float*)d_in[4];
    const float* bq    = (const float*)d_in[5];
    const float* Wk    = (const float*)d_in[6];
    const float* bk    = (const float*)d_in[7];
    const float* Wv    = (const float*)d_in[8];
    const float* bv    = (const float*)d_in[9];
    const float* Wd    = (const float*)d_in[10];
    const float* bd    = (const float*)d_in[11];
    const float* Wa    = (const float*)d_in[12];
    const float* ba    = (const float*)d_in[13];
    const float* Wo    = (const float*)d_in[14];
    const float* bo    = (const float*)d_in[15];
    const float* ln_g  = (const float*)d_in[16];
    const float* ln_b  = (const float*)d_in[17];

    float* outp  = (float*)d_out;                        // [B,S,D]
    float* probs = (float*)d_out + (size_t)B_ * S_ * D_; // [B,H,S,S]

    char* ws = (char*)d_ws;
    ushort_t* Xb    = (ushort_t*)(ws + 0);          // 2,359,296 B
    ushort_t* Wb    = (ushort_t*)(ws + 2359296);    // 4,718,592 B
    ushort_t* Qb    = (ushort_t*)(ws + 7077888);    // 2,359,296 B
    ushort_t* Kb    = (ushort_t*)(ws + 9437184);    // 2,359,296 B  [bh][grp][s][8]
    ushort_t* Vtb   = (ushort_t*)(ws + 11796480);   // 2,359,296 B  Vf fragment order
    ushort_t* Ctxb  = (ushort_t*)(ws + 14155776);   // 2,359,296 B
    float*    xbuf  = (float*)   (ws + 16662528);   // 4,718,592 B (end ~21.4 MB)
    // Dh/Ah (fp16 transposed-packed dist/ang) alias xbuf: written by k_qkvt,
    // read by k_flash, dead once k_out overwrites xbuf (stream-ordered).
    ushort_t* Dh    = (ushort_t*)(ws + 16662528);   // 2,359,296 B
    ushort_t* Ah    = (ushort_t*)(ws + 16662528 + 2359296);

    k_convert<<<3456, 256, 0, stream>>>(X, Wq, Wk, Wv, Wo, Xb, Wb);
    k_qkvt<<<792, 512, 0, stream>>>(Xb, Wb, bq, bk, bv, distm, angm, Qb, Kb, Vtb, Dh, Ah);
    k_flash<<<768, 256, 0, stream>>>(Qb, Kb, Vtb, Wd, bd, Wa, ba, Dh, Ah, mask, probs, Ctxb);
    k_out<<<dim3(12, 24), 256, 0, stream>>>(Ctxb, Wb + (size_t)2304 * 768, bo, X, xbuf);
    k_ln<<<1536, 256, 0, stream>>>(xbuf, ln_g, ln_b, outp);
}